// Round 4
// baseline (279.083 us; speedup 1.0000x reference)
//
#include <hip/hip_runtime.h>
#include <hip/hip_bf16.h>
#include <math.h>

// Tucker MoE: T=1024, D=1024, DFF=1024, R=64, G=8, E=32, NEXP=256, K=8, F=8192
// Round 4: consolidation. 15 dispatches -> 9; delete lp/act/outf round-trips.
//  - k_prep: all casts + zero counters (1 launch)
//  - k_router: logits + top-k fused (logits stay in registers)
//  - k_sortscan: scan + scatter, one block, LDS atomics
//  - k_fused_ad: act(gate/up MFMA + silu*mul) fused with down MFMA; act tile
//    lives only in LDS (C->A layout round-trip, own-wave rows => no barrier)
//  - k_outf_atomic: output GEMM epilogue atomically accumulates into out[t]
// bf16 MFMA 16x16x32 fp32-acc for all big GEMMs; router/core matvecs fp32.

#define T_ 1024
#define D_ 1024
#define DFF_ 1024
#define R_ 64
#define G_ 8
#define E_ 32
#define NEXP_ 256
#define K_ 8
#define F_ 8192
#define PKZ_ 2   // k_pre split-K
#define DKZ_ 4   // down split-K (chunks of 256 over DFF)
#define LP_ 72   // LDS tile pitch in bf16 elems (16B-aligned rows, 2-way bank alias = free)

typedef short bf16x8 __attribute__((ext_vector_type(8)));
typedef float f32x4 __attribute__((ext_vector_type(4)));

__device__ __forceinline__ unsigned short f2bf(float f) {
  unsigned int u = __float_as_uint(f);
  u += 0x7fffu + ((u >> 16) & 1u);  // RNE (finite inputs)
  return (unsigned short)(u >> 16);
}

// Stage a 64x64 bf16 tile (global row-major, pitch gp elems) into LDS pitch-72.
__device__ __forceinline__ void stage_tile(short* dst, const unsigned short* src,
                                           int gp, int tid) {
  for (int idx = tid; idx < 512; idx += 256) {
    int r = idx >> 3, c8 = (idx & 7) << 3;
    *(uint4*)&dst[r * LP_ + c8] = *(const uint4*)&src[(size_t)r * gp + c8];
  }
}

__device__ __forceinline__ void stage_tile_guard(short* dst, const unsigned short* src,
                                                 int gp, int rows_valid, int tid) {
  for (int idx = tid; idx < 512; idx += 256) {
    int r = idx >> 3, c8 = (idx & 7) << 3;
    uint4 v = make_uint4(0u, 0u, 0u, 0u);
    if (r < rows_valid) v = *(const uint4*)&src[(size_t)r * gp + c8];
    *(uint4*)&dst[r * LP_ + c8] = v;
  }
}

// Wave computes a 16x64 strip (rows [ms,ms+16)) over K=64 from LDS tiles
// As (rows=m, k-contig) and Bs (rows=n, k-contig; i.e. B^T).
__device__ __forceinline__ void mma_strip(const short* As, const short* Bs,
                                          int ms, int lane, f32x4* acc) {
  int lm = lane & 15;
  int lk = (lane >> 4) << 3;
#pragma unroll
  for (int kc = 0; kc < 64; kc += 32) {
    bf16x8 a = *(const bf16x8*)&As[(ms + lm) * LP_ + kc + lk];
#pragma unroll
    for (int nt = 0; nt < 4; ++nt) {
      bf16x8 b = *(const bf16x8*)&Bs[(nt * 16 + lm) * LP_ + kc + lk];
      acc[nt] = __builtin_amdgcn_mfma_f32_16x16x32_bf16(a, b, acc[nt], 0, 0, 0);
    }
  }
}

// ---------------------------------------------------------------- prep: all casts + zero counters
// grid (16, G, 7): z<6 weight cast+transpose; z==6 x cast (+ counter zero in one block)
__global__ __launch_bounds__(256) void k_prep(const float* __restrict__ x,
                                              const float* __restrict__ s0, const float* __restrict__ s1,
                                              const float* __restrict__ s2, const float* __restrict__ s3,
                                              const float* __restrict__ s4, const float* __restrict__ s5,
                                              unsigned short* __restrict__ xb,
                                              unsigned short* __restrict__ d0, unsigned short* __restrict__ d1,
                                              unsigned short* __restrict__ d2, unsigned short* __restrict__ d3,
                                              unsigned short* __restrict__ d4, unsigned short* __restrict__ d5,
                                              int* __restrict__ cnt, int* __restrict__ cur) {
  int id = blockIdx.z, g = blockIdx.y, tile = blockIdx.x;
  if (id == 6) {
    // x cast: 128 blocks x 2048 float4
    size_t base = ((size_t)g * 16 + tile) * 8192;
    for (int i = threadIdx.x; i < 2048; i += 256) {
      size_t idx = base + (size_t)i * 4;
      float4 v = *(const float4*)&x[idx];
      xb[idx + 0] = f2bf(v.x);
      xb[idx + 1] = f2bf(v.y);
      xb[idx + 2] = f2bf(v.z);
      xb[idx + 3] = f2bf(v.w);
    }
    if (g == 0 && tile == 0) { cnt[threadIdx.x] = 0; cur[threadIdx.x] = 0; }
    return;
  }
  __shared__ float ts[64][65];
  const float* src = id == 0 ? s0 : id == 1 ? s1 : id == 2 ? s2 : id == 3 ? s3 : id == 4 ? s4 : s5;
  unsigned short* dst = id == 0 ? d0 : id == 1 ? d1 : id == 2 ? d2 : id == 3 ? d3 : id == 4 ? d4 : d5;
  if (id < 3) {
    // uin*: src [g][1024][64] -> dst [g][64][1024]
    int r0 = tile * 64;
    for (int idx = threadIdx.x; idx < 4096; idx += 256) {
      int r = idx >> 6, c = idx & 63;
      ts[r][c] = src[((size_t)g * 1024 + r0 + r) * 64 + c];
    }
    __syncthreads();
    for (int idx = threadIdx.x; idx < 4096; idx += 256) {
      int c = idx >> 6, r = idx & 63;
      dst[((size_t)g * 64 + c) * 1024 + r0 + r] = f2bf(ts[r][c]);
    }
  } else {
    // uout*: src [g][64][1024] -> dst [g][1024][64]
    int c0 = tile * 64;
    for (int idx = threadIdx.x; idx < 4096; idx += 256) {
      int r = idx >> 6, c = idx & 63;
      ts[r][c] = src[((size_t)g * 64 + r) * 1024 + c0 + c];
    }
    __syncthreads();
    for (int idx = threadIdx.x; idx < 4096; idx += 256) {
      int c = idx >> 6, r = idx & 63;
      dst[((size_t)g * 1024 + c0 + c) * 64 + r] = f2bf(ts[r][c]);
    }
  }
}

// ---------------------------------------------------------------- router: logits + top-k fused
// 256 blocks x 4 tokens. Wave w = token t0+w; lane l covers experts 4l..4l+3
// (float4 Wg loads, same addresses across waves -> L1 hits). Logits never
// leave registers. fp32 so selection matches the fp32 reference router.
__global__ __launch_bounds__(256) void k_router(const float* __restrict__ x,
                                                const float* __restrict__ Wg,
                                                int* __restrict__ sel,
                                                float* __restrict__ wsm,
                                                int* __restrict__ cnt) {
  __shared__ float xs[4][64];
  int t0 = blockIdx.x * 4;
  int wave = threadIdx.x >> 6;
  int lane = threadIdx.x & 63;
  int t = t0 + wave;
  float a[4] = {0.f, 0.f, 0.f, 0.f};
  for (int dc = 0; dc < D_; dc += 64) {
    int tl = threadIdx.x >> 6, d = threadIdx.x & 63;
    xs[tl][d] = x[(size_t)(t0 + tl) * D_ + dc + d];
    __syncthreads();
#pragma unroll 8
    for (int d2 = 0; d2 < 64; ++d2) {
      float4 w4 = *(const float4*)&Wg[(size_t)(dc + d2) * NEXP_ + lane * 4];
      float xv = xs[wave][d2];
      a[0] = fmaf(xv, w4.x, a[0]);
      a[1] = fmaf(xv, w4.y, a[1]);
      a[2] = fmaf(xv, w4.z, a[2]);
      a[3] = fmaf(xv, w4.w, a[3]);
    }
    __syncthreads();
  }
  // top-8 with lower-index tie-break (jax.lax.top_k semantics)
  float v[4];
  int idx[4];
#pragma unroll
  for (int j = 0; j < 4; ++j) { v[j] = a[j]; idx[j] = lane * 4 + j; }
  float topv[K_];
  int topi[K_];
#pragma unroll
  for (int k = 0; k < K_; ++k) {
    float bv = v[0];
    int bi = idx[0];
#pragma unroll
    for (int j = 1; j < 4; ++j)
      if (v[j] > bv || (v[j] == bv && idx[j] < bi)) { bv = v[j]; bi = idx[j]; }
#pragma unroll
    for (int off = 32; off > 0; off >>= 1) {
      float ov = __shfl_xor(bv, off);
      int oi = __shfl_xor(bi, off);
      if (ov > bv || (ov == bv && oi < bi)) { bv = ov; bi = oi; }
    }
    topv[k] = bv;
    topi[k] = bi;
#pragma unroll
    for (int j = 0; j < 4; ++j)
      if (idx[j] == bi) v[j] = -INFINITY;
  }
  float m = topv[0];
  float ev[K_];
  float s = 0.f;
#pragma unroll
  for (int k = 0; k < K_; ++k) { ev[k] = expf(topv[k] - m); s += ev[k]; }
  float inv = 1.f / s;
  if (lane < K_) {
    sel[t * K_ + lane] = topi[lane];
    wsm[t * K_ + lane] = ev[lane] * inv;
    atomicAdd(&cnt[topi[lane]], 1);
  }
}

// ---------------------------------------------------------------- scan + scatter, one block
__global__ __launch_bounds__(256) void k_sortscan(const int* __restrict__ cnt,
                                                  const int* __restrict__ sel,
                                                  const float* __restrict__ wsm,
                                                  int* __restrict__ off,
                                                  int* __restrict__ stok,
                                                  int* __restrict__ se,
                                                  float* __restrict__ sw) {
  __shared__ int s[NEXP_];
  __shared__ int offl[NEXP_];
  __shared__ int curl[NEXP_];
  int i = threadIdx.x;
  s[i] = cnt[i];
  __syncthreads();
  for (int d = 1; d < NEXP_; d <<= 1) {
    int v = (i >= d) ? s[i - d] : 0;
    __syncthreads();
    s[i] += v;
    __syncthreads();
  }
  offl[i] = s[i] - cnt[i];  // exclusive
  curl[i] = 0;
  off[i + 1] = s[i];
  if (i == 0) off[0] = 0;
  __syncthreads();
  for (int f = i; f < F_; f += 256) {
    int e = sel[f];
    int p = offl[e] + atomicAdd(&curl[e], 1);
    stok[p] = f >> 3;
    se[p] = e;
    sw[p] = wsm[f];
  }
}

// ---------------------------------------------------------------- pre (MFMA, split-K 2)
__global__ __launch_bounds__(256) void k_pre_mfma(const unsigned short* __restrict__ xb,
                                                  const unsigned short* __restrict__ uinT_g,
                                                  const unsigned short* __restrict__ uinT_u,
                                                  float* __restrict__ Pgp,
                                                  float* __restrict__ Pup) {
  int g = blockIdx.y;
  int gu = blockIdx.z >> 1, kz = blockIdx.z & 1;
  const unsigned short* U = gu ? uinT_u : uinT_g;  // [G][64(r)][1024(d)]
  float* P = gu ? Pup : Pgp;
  int t0 = blockIdx.x * 64;
  __shared__ short As[64 * LP_], Bs[64 * LP_];
  int tid = threadIdx.x, lane = tid & 63, ms = (tid >> 6) * 16;
  f32x4 acc[4] = {};
  int dlo = kz * (D_ / PKZ_);
  for (int dc = dlo; dc < dlo + D_ / PKZ_; dc += 64) {
    stage_tile(As, xb + (size_t)t0 * D_ + dc, D_, tid);
    stage_tile(Bs, U + (size_t)g * 64 * 1024 + dc, 1024, tid);
    __syncthreads();
    mma_strip(As, Bs, ms, lane, acc);
    __syncthreads();
  }
  int lm = lane & 15, lq = (lane >> 4) * 4;
#pragma unroll
  for (int nt = 0; nt < 4; ++nt)
#pragma unroll
    for (int r = 0; r < 4; ++r)
      P[((size_t)(kz * G_ + g) * T_ + t0 + ms + lq + r) * R_ + nt * 16 + lm] = acc[nt][r];
}

// ---------------------------------------------------------------- core gate/up (fp32) -> bf16
__global__ __launch_bounds__(256) void k_core_gu(const float* __restrict__ Pgp,
                                                 const float* __restrict__ Pup,
                                                 const float* __restrict__ core_g,
                                                 const float* __restrict__ core_u,
                                                 const int* __restrict__ stok,
                                                 const int* __restrict__ se,
                                                 unsigned short* __restrict__ xgb,
                                                 unsigned short* __restrict__ xub) {
  int pl = threadIdx.x >> 6;
  int o = threadIdx.x & 63;
  int p = blockIdx.x * 4 + pl;
  int e = se[p];
  int t = stok[p];
  int g = e >> 5;
  __shared__ float rg[4][64], ru[4][64];
  float sg = 0.f, su = 0.f;
#pragma unroll
  for (int kz = 0; kz < PKZ_; ++kz) {
    sg += Pgp[((size_t)(kz * G_ + g) * T_ + t) * R_ + o];
    su += Pup[((size_t)(kz * G_ + g) * T_ + t) * R_ + o];
  }
  rg[pl][o] = sg;
  ru[pl][o] = su;
  __syncthreads();
  const float* cg = core_g + (size_t)e * R_ * R_;
  const float* cu = core_u + (size_t)e * R_ * R_;
  float ag = 0.f, au = 0.f;
#pragma unroll 8
  for (int r = 0; r < R_; ++r) {
    ag = fmaf(rg[pl][r], cg[r * R_ + o], ag);
    au = fmaf(ru[pl][r], cu[r * R_ + o], au);
  }
  xgb[(size_t)p * R_ + o] = f2bf(ag);
  xub[(size_t)p * R_ + o] = f2bf(au);
}

// ---------------------------------------------------------------- fused act+down (MFMA)
// grid (16, G, DKZ_). Per 64-pair tile, loop 4x 64-col chunks of this kz's
// 256-col DFF slice: MFMA gate/up -> silu*mul -> bf16 act tile in LDS
// (C-layout write, A-layout read, own-wave rows only) -> MFMA acc into xd
// partial. act never touches HBM.
__global__ __launch_bounds__(256) void k_fused_ad(const unsigned short* __restrict__ xgb,
                                                  const unsigned short* __restrict__ xub,
                                                  const unsigned short* __restrict__ uoutT_g,
                                                  const unsigned short* __restrict__ uoutT_u,
                                                  const unsigned short* __restrict__ uinT_d,
                                                  const int* __restrict__ off,
                                                  float* __restrict__ xdp) {
  int g = blockIdx.y;
  int kz = blockIdx.z;
  int p0 = off[g * E_];
  int pend = off[g * E_ + E_];
  int ntiles = (pend - p0 + 63) >> 6;
  __shared__ short Ag[64 * LP_], Au[64 * LP_];
  __shared__ short Bg[64 * LP_], Bu[64 * LP_], Bd[64 * LP_];
  __shared__ short Pt[64 * LP_];
  int tid = threadIdx.x, lane = tid & 63, ms = (tid >> 6) * 16;
  int lm = lane & 15, lq = (lane >> 4) * 4;
  for (int tile = blockIdx.x; tile < ntiles; tile += gridDim.x) {
    int pbase = p0 + tile * 64;
    int rv = pend - pbase; if (rv > 64) rv = 64;
    stage_tile_guard(Ag, xgb + (size_t)pbase * R_, R_, rv, tid);
    stage_tile_guard(Au, xub + (size_t)pbase * R_, R_, rv, tid);
    f32x4 accd[4] = {};
#pragma unroll
    for (int c4 = 0; c4 < 4; ++c4) {
      int cc = kz * (DFF_ / DKZ_) + c4 * 64;
      stage_tile(Bg, uoutT_g + ((size_t)g * DFF_ + cc) * R_, R_, tid);
      stage_tile(Bu, uoutT_u + ((size_t)g * DFF_ + cc) * R_, R_, tid);
      stage_tile(Bd, uinT_d + (size_t)g * 64 * 1024 + cc, 1024, tid);
      __syncthreads();
      f32x4 accg[4] = {}, accu[4] = {};
      mma_strip(Ag, Bg, ms, lane, accg);
      mma_strip(Au, Bu, ms, lane, accu);
      // silu(gate)*up -> bf16 act tile rows [ms,ms+16) (own wave only)
#pragma unroll
      for (int nt = 0; nt < 4; ++nt)
#pragma unroll
        for (int r = 0; r < 4; ++r) {
          float gv = accg[nt][r];
          float av = gv / (1.f + expf(-gv)) * accu[nt][r];
          Pt[(ms + lq + r) * LP_ + nt * 16 + lm] = (short)f2bf(av);
        }
      // down-mma reads only own-wave rows of Pt (+ Bd staged above)
      mma_strip(Pt, Bd, ms, lane, accd);
      __syncthreads();
    }
#pragma unroll
    for (int nt = 0; nt < 4; ++nt)
#pragma unroll
      for (int r = 0; r < 4; ++r) {
        int p = pbase + ms + lq + r;
        if (p < pend) xdp[((size_t)kz * F_ + p) * R_ + nt * 16 + lm] = accd[nt][r];
      }
    __syncthreads();
  }
}

// ---------------------------------------------------------------- fold + down core (fp32) -> bf16
__global__ __launch_bounds__(256) void k_core_down(const float* __restrict__ xdp,
                                                   const float* __restrict__ core_d,
                                                   const int* __restrict__ se,
                                                   unsigned short* __restrict__ xd2b) {
  int pl = threadIdx.x >> 6;
  int o = threadIdx.x & 63;
  int p = blockIdx.x * 4 + pl;
  int e = se[p];
  __shared__ float rg[4][64];
  float s = 0.f;
#pragma unroll
  for (int kz = 0; kz < DKZ_; ++kz) s += xdp[((size_t)kz * F_ + p) * R_ + o];
  rg[pl][o] = s;
  __syncthreads();
  const float* cd = core_d + (size_t)e * R_ * R_;
  float a = 0.f;
#pragma unroll 8
  for (int r = 0; r < R_; ++r) a = fmaf(rg[pl][r], cd[r * R_ + o], a);
  xd2b[(size_t)p * R_ + o] = f2bf(a);
}

// ---------------------------------------------------------------- outf (MFMA) + gather via atomics
// grid (16, G, D/64). out[t] += w[p] * (xd2[p] @ uout_down[g]) directly.
__global__ __launch_bounds__(256) void k_outf_atomic(const unsigned short* __restrict__ xd2b,
                                                     const unsigned short* __restrict__ uoutT_d,
                                                     const int* __restrict__ off,
                                                     const float* __restrict__ sw,
                                                     const int* __restrict__ stok,
                                                     float* __restrict__ out) {
  int g = blockIdx.y;
  int p0 = off[g * E_];
  int pend = off[g * E_ + E_];
  int ntiles = (pend - p0 + 63) >> 6;
  int c0 = blockIdx.z * 64;
  __shared__ short As[64 * LP_], Bs[64 * LP_];
  int tid = threadIdx.x, lane = tid & 63, ms = (tid >> 6) * 16;
  int lm = lane & 15, lq = (lane >> 4) * 4;
  for (int tile = blockIdx.x; tile < ntiles; tile += gridDim.x) {
    int pbase = p0 + tile * 64;
    int rv = pend - pbase; if (rv > 64) rv = 64;
    stage_tile_guard(As, xd2b + (size_t)pbase * R_, R_, rv, tid);
    stage_tile(Bs, uoutT_d + ((size_t)g * D_ + c0) * R_, R_, tid);
    __syncthreads();
    f32x4 acc[4] = {};
    mma_strip(As, Bs, ms, lane, acc);
#pragma unroll
    for (int r = 0; r < 4; ++r) {
      int p = pbase + ms + lq + r;
      if (p < pend) {
        float wv = sw[p];
        int t = stok[p];
#pragma unroll
        for (int nt = 0; nt < 4; ++nt)
          atomicAdd(&out[(size_t)t * D_ + c0 + nt * 16 + lm], acc[nt][r] * wv);
      }
    }
    __syncthreads();
  }
}

// ================================================================ launch
extern "C" void kernel_launch(void* const* d_in, const int* in_sizes, int n_in,
                              void* d_out, int out_size, void* d_ws, size_t ws_size,
                              hipStream_t stream) {
  const float* x = (const float*)d_in[0];
  const float* Wg = (const float*)d_in[1];
  const float* uin_gate = (const float*)d_in[2];
  const float* core_gate = (const float*)d_in[3];
  const float* uout_gate = (const float*)d_in[4];
  const float* uin_up = (const float*)d_in[5];
  const float* core_up = (const float*)d_in[6];
  const float* uout_up = (const float*)d_in[7];
  const float* uin_down = (const float*)d_in[8];
  const float* core_down = (const float*)d_in[9];
  const float* uout_down = (const float*)d_in[10];
  float* out = (float*)d_out;

  char* ws = (char*)d_ws;
  size_t o = 0;
  auto alloc = [&](size_t bytes) { size_t r = o; o = (o + bytes + 255) & ~(size_t)255; return r; };
  size_t o_sel = alloc(F_ * 4);
  size_t o_wsm = alloc(F_ * 4);
  size_t o_cnt = alloc(NEXP_ * 4);
  size_t o_cur = alloc(NEXP_ * 4);
  size_t o_off = alloc((NEXP_ + 1) * 4);
  size_t o_stok = alloc(F_ * 4);
  size_t o_se = alloc(F_ * 4);
  size_t o_sw = alloc(F_ * 4);
  size_t o_xb = alloc((size_t)T_ * D_ * 2);                     // 2 MB
  size_t o_uinT_g = alloc((size_t)G_ * 64 * 1024 * 2);          // 1 MB each
  size_t o_uinT_u = alloc((size_t)G_ * 64 * 1024 * 2);
  size_t o_uinT_d = alloc((size_t)G_ * 64 * 1024 * 2);
  size_t o_uoutT_g = alloc((size_t)G_ * 1024 * 64 * 2);
  size_t o_uoutT_u = alloc((size_t)G_ * 1024 * 64 * 2);
  size_t o_uoutT_d = alloc((size_t)G_ * 1024 * 64 * 2);
  size_t o_xgb = alloc((size_t)F_ * R_ * 2);                    // 1 MB
  size_t o_xub = alloc((size_t)F_ * R_ * 2);
  size_t o_xd2b = alloc((size_t)F_ * R_ * 2);
  size_t o_pgp = alloc((size_t)PKZ_ * G_ * T_ * R_ * 4);        // 4 MB
  size_t o_pup = alloc((size_t)PKZ_ * G_ * T_ * R_ * 4);        // 4 MB
  size_t o_xdp = alloc((size_t)DKZ_ * F_ * R_ * 4);             // 8 MB
  (void)ws_size;

  int* sel = (int*)(ws + o_sel);
  float* wsm = (float*)(ws + o_wsm);
  int* cnt = (int*)(ws + o_cnt);
  int* cur = (int*)(ws + o_cur);
  int* off = (int*)(ws + o_off);
  int* stok = (int*)(ws + o_stok);
  int* se = (int*)(ws + o_se);
  float* sw = (float*)(ws + o_sw);
  unsigned short* xb = (unsigned short*)(ws + o_xb);
  unsigned short* uinT_g = (unsigned short*)(ws + o_uinT_g);
  unsigned short* uinT_u = (unsigned short*)(ws + o_uinT_u);
  unsigned short* uinT_d = (unsigned short*)(ws + o_uinT_d);
  unsigned short* uoutT_g = (unsigned short*)(ws + o_uoutT_g);
  unsigned short* uoutT_u = (unsigned short*)(ws + o_uoutT_u);
  unsigned short* uoutT_d = (unsigned short*)(ws + o_uoutT_d);
  unsigned short* xgb = (unsigned short*)(ws + o_xgb);
  unsigned short* xub = (unsigned short*)(ws + o_xub);
  unsigned short* xd2b = (unsigned short*)(ws + o_xd2b);
  float* pgp = (float*)(ws + o_pgp);
  float* pup = (float*)(ws + o_pup);
  float* xdp = (float*)(ws + o_xdp);

  hipMemsetAsync(out, 0, (size_t)T_ * D_ * 4, stream);  // atomic accumulate target

  k_prep<<<dim3(16, G_, 7), 256, 0, stream>>>(x, uin_gate, uin_up, uin_down,
                                              uout_gate, uout_up, uout_down, xb,
                                              uinT_g, uinT_u, uinT_d,
                                              uoutT_g, uoutT_u, uoutT_d, cnt, cur);
  k_router<<<T_ / 4, 256, 0, stream>>>(x, Wg, sel, wsm, cnt);
  k_sortscan<<<1, 256, 0, stream>>>(cnt, sel, wsm, off, stok, se, sw);
  k_pre_mfma<<<dim3(T_ / 64, G_, 2 * PKZ_), 256, 0, stream>>>(xb, uinT_g, uinT_u, pgp, pup);
  k_core_gu<<<F_ / 4, 256, 0, stream>>>(pgp, pup, core_gate, core_up, stok, se, xgb, xub);
  k_fused_ad<<<dim3(16, G_, DKZ_), 256, 0, stream>>>(xgb, xub, uoutT_g, uoutT_u, uinT_d, off, xdp);
  k_core_down<<<F_ / 4, 256, 0, stream>>>(xdp, core_down, se, xd2b);
  k_outf_atomic<<<dim3(16, G_, D_ / 64), 256, 0, stream>>>(xd2b, uoutT_d, off, sw, stok, out);
}

// Round 6
// 254.629 us; speedup vs baseline: 1.0960x; 1.0960x over previous
//
#include <hip/hip_runtime.h>
#include <hip/hip_bf16.h>
#include <math.h>

// Tucker MoE: T=1024, D=1024, DFF=1024, R=64, G=8, E=32, NEXP=256, K=8, F=8192
// Round 6: R5 with the k_logits staging OOB fixed (one 1024-float pass, not
// two; the second pass wrote 4KB past xs[] and read x[] OOB -> core dump).
// Structure: R4's consolidated graph + split-K router.
//  - k_prep: all casts + zero counters
//  - k_logits/k_topk: split-K fp32 router (1024 blocks, 8 FMA per Wg load)
//  - k_fused_ad: act(gate/up MFMA + silu*mul) fused with down MFMA in LDS
//  - k_outf_atomic: output GEMM epilogue accumulates into out[t] directly
// bf16 MFMA 16x16x32 fp32-acc for big GEMMs; router/core matvecs fp32.

#define T_ 1024
#define D_ 1024
#define DFF_ 1024
#define R_ 64
#define G_ 8
#define E_ 32
#define NEXP_ 256
#define K_ 8
#define F_ 8192
#define LKZ_ 8   // router split-K (chunks of 128)
#define LTB_ 8   // router tokens per block
#define PKZ_ 2   // k_pre split-K
#define DKZ_ 4   // down split-K (chunks of 256 over DFF)
#define LP_ 72   // LDS tile pitch in bf16 elems (16B-aligned rows, 2-way bank alias = free)

typedef short bf16x8 __attribute__((ext_vector_type(8)));
typedef float f32x4 __attribute__((ext_vector_type(4)));

__device__ __forceinline__ unsigned short f2bf(float f) {
  unsigned int u = __float_as_uint(f);
  u += 0x7fffu + ((u >> 16) & 1u);  // RNE (finite inputs)
  return (unsigned short)(u >> 16);
}

// Stage a 64x64 bf16 tile (global row-major, pitch gp elems) into LDS pitch-72.
__device__ __forceinline__ void stage_tile(short* dst, const unsigned short* src,
                                           int gp, int tid) {
  for (int idx = tid; idx < 512; idx += 256) {
    int r = idx >> 3, c8 = (idx & 7) << 3;
    *(uint4*)&dst[r * LP_ + c8] = *(const uint4*)&src[(size_t)r * gp + c8];
  }
}

__device__ __forceinline__ void stage_tile_guard(short* dst, const unsigned short* src,
                                                 int gp, int rows_valid, int tid) {
  for (int idx = tid; idx < 512; idx += 256) {
    int r = idx >> 3, c8 = (idx & 7) << 3;
    uint4 v = make_uint4(0u, 0u, 0u, 0u);
    if (r < rows_valid) v = *(const uint4*)&src[(size_t)r * gp + c8];
    *(uint4*)&dst[r * LP_ + c8] = v;
  }
}

// Wave computes a 16x64 strip (rows [ms,ms+16)) over K=64 from LDS tiles
// As (rows=m, k-contig) and Bs (rows=n, k-contig; i.e. B^T).
__device__ __forceinline__ void mma_strip(const short* As, const short* Bs,
                                          int ms, int lane, f32x4* acc) {
  int lm = lane & 15;
  int lk = (lane >> 4) << 3;
#pragma unroll
  for (int kc = 0; kc < 64; kc += 32) {
    bf16x8 a = *(const bf16x8*)&As[(ms + lm) * LP_ + kc + lk];
#pragma unroll
    for (int nt = 0; nt < 4; ++nt) {
      bf16x8 b = *(const bf16x8*)&Bs[(nt * 16 + lm) * LP_ + kc + lk];
      acc[nt] = __builtin_amdgcn_mfma_f32_16x16x32_bf16(a, b, acc[nt], 0, 0, 0);
    }
  }
}

// ---------------------------------------------------------------- prep: all casts + zero counters
// grid (16, G, 7): z<6 weight cast+transpose; z==6 x cast (+ counter zero in one block)
__global__ __launch_bounds__(256) void k_prep(const float* __restrict__ x,
                                              const float* __restrict__ s0, const float* __restrict__ s1,
                                              const float* __restrict__ s2, const float* __restrict__ s3,
                                              const float* __restrict__ s4, const float* __restrict__ s5,
                                              unsigned short* __restrict__ xb,
                                              unsigned short* __restrict__ d0, unsigned short* __restrict__ d1,
                                              unsigned short* __restrict__ d2, unsigned short* __restrict__ d3,
                                              unsigned short* __restrict__ d4, unsigned short* __restrict__ d5,
                                              int* __restrict__ cnt, int* __restrict__ cur) {
  int id = blockIdx.z, g = blockIdx.y, tile = blockIdx.x;
  if (id == 6) {
    size_t base = ((size_t)g * 16 + tile) * 8192;
    for (int i = threadIdx.x; i < 2048; i += 256) {
      size_t idx = base + (size_t)i * 4;
      float4 v = *(const float4*)&x[idx];
      xb[idx + 0] = f2bf(v.x);
      xb[idx + 1] = f2bf(v.y);
      xb[idx + 2] = f2bf(v.z);
      xb[idx + 3] = f2bf(v.w);
    }
    if (g == 0 && tile == 0) { cnt[threadIdx.x] = 0; cur[threadIdx.x] = 0; }
    return;
  }
  __shared__ float ts[64][65];
  const float* src = id == 0 ? s0 : id == 1 ? s1 : id == 2 ? s2 : id == 3 ? s3 : id == 4 ? s4 : s5;
  unsigned short* dst = id == 0 ? d0 : id == 1 ? d1 : id == 2 ? d2 : id == 3 ? d3 : id == 4 ? d4 : d5;
  if (id < 3) {
    // uin*: src [g][1024][64] -> dst [g][64][1024]
    int r0 = tile * 64;
    for (int idx = threadIdx.x; idx < 4096; idx += 256) {
      int r = idx >> 6, c = idx & 63;
      ts[r][c] = src[((size_t)g * 1024 + r0 + r) * 64 + c];
    }
    __syncthreads();
    for (int idx = threadIdx.x; idx < 4096; idx += 256) {
      int c = idx >> 6, r = idx & 63;
      dst[((size_t)g * 64 + c) * 1024 + r0 + r] = f2bf(ts[r][c]);
    }
  } else {
    // uout*: src [g][64][1024] -> dst [g][1024][64]
    int c0 = tile * 64;
    for (int idx = threadIdx.x; idx < 4096; idx += 256) {
      int r = idx >> 6, c = idx & 63;
      ts[r][c] = src[((size_t)g * 64 + r) * 1024 + c0 + c];
    }
    __syncthreads();
    for (int idx = threadIdx.x; idx < 4096; idx += 256) {
      int c = idx >> 6, r = idx & 63;
      dst[((size_t)g * 1024 + c0 + c) * 64 + r] = f2bf(ts[r][c]);
    }
  }
}

// ---------------------------------------------------------------- router GEMM (fp32, split-K)
// lp[z][t][e] = sum_{d in chunk z(128)} x[t][d] * Wg[d][e].  8 tokens/block,
// thread = expert: 1 coalesced Wg load per 8 FMAs; 1024 blocks.
__global__ __launch_bounds__(256) void k_logits(const float* __restrict__ x,
                                                const float* __restrict__ Wg,
                                                float* __restrict__ lp) {
  __shared__ float xs[LTB_][128];
  int t0 = blockIdx.x * LTB_;
  int z = blockIdx.y;
  int e = threadIdx.x;
  float a[LTB_] = {};
  int dc = z * 128;
  {
    // 256 threads x float4 = 1024 floats = the whole 8x128 tile (ONE pass)
    int idx = threadIdx.x * 4;
    int tl = idx >> 7, d = idx & 127;
    *(float4*)&xs[tl][d] = *(const float4*)&x[(size_t)(t0 + tl) * D_ + dc + d];
  }
  __syncthreads();
#pragma unroll 8
  for (int d2 = 0; d2 < 128; ++d2) {
    float wv = Wg[(size_t)(dc + d2) * NEXP_ + e];
#pragma unroll
    for (int j = 0; j < LTB_; ++j) a[j] = fmaf(xs[j][d2], wv, a[j]);
  }
  size_t base = (size_t)z * T_ * NEXP_;
#pragma unroll
  for (int j = 0; j < LTB_; ++j)
    lp[base + (size_t)(t0 + j) * NEXP_ + e] = a[j];
}

// ---------------------------------------------------------------- top-k + softmax (fp32)
// One 64-lane wave per token; folds the LKZ_ logits partials on load.
__global__ __launch_bounds__(256) void k_topk(const float* __restrict__ lp,
                                              int* __restrict__ sel,
                                              float* __restrict__ wsm,
                                              int* __restrict__ cnt) {
  int wave = threadIdx.x >> 6;
  int lane = threadIdx.x & 63;
  int t = blockIdx.x * 4 + wave;

  float v[4];
  int idx[4];
#pragma unroll
  for (int j = 0; j < 4; ++j) {
    idx[j] = lane + 64 * j;
    float s = 0.f;
#pragma unroll
    for (int z = 0; z < LKZ_; ++z)
      s += lp[(size_t)z * T_ * NEXP_ + (size_t)t * NEXP_ + idx[j]];
    v[j] = s;
  }

  float topv[K_];
  int topi[K_];
#pragma unroll
  for (int k = 0; k < K_; ++k) {
    float bv = v[0];
    int bi = idx[0];
#pragma unroll
    for (int j = 1; j < 4; ++j)
      if (v[j] > bv || (v[j] == bv && idx[j] < bi)) { bv = v[j]; bi = idx[j]; }
#pragma unroll
    for (int off = 32; off > 0; off >>= 1) {
      float ov = __shfl_xor(bv, off);
      int oi = __shfl_xor(bi, off);
      if (ov > bv || (ov == bv && oi < bi)) { bv = ov; bi = oi; }
    }
    topv[k] = bv;
    topi[k] = bi;
#pragma unroll
    for (int j = 0; j < 4; ++j)
      if (idx[j] == bi) v[j] = -INFINITY;
  }

  float m = topv[0];
  float ev[K_];
  float s = 0.f;
#pragma unroll
  for (int k = 0; k < K_; ++k) { ev[k] = expf(topv[k] - m); s += ev[k]; }
  float inv = 1.f / s;
  if (lane < K_) {
    sel[t * K_ + lane] = topi[lane];
    wsm[t * K_ + lane] = ev[lane] * inv;
    atomicAdd(&cnt[topi[lane]], 1);
  }
}

// ---------------------------------------------------------------- scan + scatter, one block
__global__ __launch_bounds__(256) void k_sortscan(const int* __restrict__ cnt,
                                                  const int* __restrict__ sel,
                                                  const float* __restrict__ wsm,
                                                  int* __restrict__ off,
                                                  int* __restrict__ stok,
                                                  int* __restrict__ se,
                                                  float* __restrict__ sw) {
  __shared__ int s[NEXP_];
  __shared__ int offl[NEXP_];
  __shared__ int curl[NEXP_];
  int i = threadIdx.x;
  s[i] = cnt[i];
  __syncthreads();
  for (int d = 1; d < NEXP_; d <<= 1) {
    int v = (i >= d) ? s[i - d] : 0;
    __syncthreads();
    s[i] += v;
    __syncthreads();
  }
  offl[i] = s[i] - cnt[i];  // exclusive
  curl[i] = 0;
  off[i + 1] = s[i];
  if (i == 0) off[0] = 0;
  __syncthreads();
  for (int f = i; f < F_; f += 256) {
    int e = sel[f];
    int p = offl[e] + atomicAdd(&curl[e], 1);
    stok[p] = f >> 3;
    se[p] = e;
    sw[p] = wsm[f];
  }
}

// ---------------------------------------------------------------- pre (MFMA, split-K 2)
__global__ __launch_bounds__(256) void k_pre_mfma(const unsigned short* __restrict__ xb,
                                                  const unsigned short* __restrict__ uinT_g,
                                                  const unsigned short* __restrict__ uinT_u,
                                                  float* __restrict__ Pgp,
                                                  float* __restrict__ Pup) {
  int g = blockIdx.y;
  int gu = blockIdx.z >> 1, kz = blockIdx.z & 1;
  const unsigned short* U = gu ? uinT_u : uinT_g;  // [G][64(r)][1024(d)]
  float* P = gu ? Pup : Pgp;
  int t0 = blockIdx.x * 64;
  __shared__ short As[64 * LP_], Bs[64 * LP_];
  int tid = threadIdx.x, lane = tid & 63, ms = (tid >> 6) * 16;
  f32x4 acc[4] = {};
  int dlo = kz * (D_ / PKZ_);
  for (int dc = dlo; dc < dlo + D_ / PKZ_; dc += 64) {
    stage_tile(As, xb + (size_t)t0 * D_ + dc, D_, tid);
    stage_tile(Bs, U + (size_t)g * 64 * 1024 + dc, 1024, tid);
    __syncthreads();
    mma_strip(As, Bs, ms, lane, acc);
    __syncthreads();
  }
  int lm = lane & 15, lq = (lane >> 4) * 4;
#pragma unroll
  for (int nt = 0; nt < 4; ++nt)
#pragma unroll
    for (int r = 0; r < 4; ++r)
      P[((size_t)(kz * G_ + g) * T_ + t0 + ms + lq + r) * R_ + nt * 16 + lm] = acc[nt][r];
}

// ---------------------------------------------------------------- core gate/up (fp32) -> bf16
__global__ __launch_bounds__(256) void k_core_gu(const float* __restrict__ Pgp,
                                                 const float* __restrict__ Pup,
                                                 const float* __restrict__ core_g,
                                                 const float* __restrict__ core_u,
                                                 const int* __restrict__ stok,
                                                 const int* __restrict__ se,
                                                 unsigned short* __restrict__ xgb,
                                                 unsigned short* __restrict__ xub) {
  int pl = threadIdx.x >> 6;
  int o = threadIdx.x & 63;
  int p = blockIdx.x * 4 + pl;
  int e = se[p];
  int t = stok[p];
  int g = e >> 5;
  __shared__ float rg[4][64], ru[4][64];
  float sg = 0.f, su = 0.f;
#pragma unroll
  for (int kz = 0; kz < PKZ_; ++kz) {
    sg += Pgp[((size_t)(kz * G_ + g) * T_ + t) * R_ + o];
    su += Pup[((size_t)(kz * G_ + g) * T_ + t) * R_ + o];
  }
  rg[pl][o] = sg;
  ru[pl][o] = su;
  __syncthreads();
  const float* cg = core_g + (size_t)e * R_ * R_;
  const float* cu = core_u + (size_t)e * R_ * R_;
  float ag = 0.f, au = 0.f;
#pragma unroll 8
  for (int r = 0; r < R_; ++r) {
    ag = fmaf(rg[pl][r], cg[r * R_ + o], ag);
    au = fmaf(ru[pl][r], cu[r * R_ + o], au);
  }
  xgb[(size_t)p * R_ + o] = f2bf(ag);
  xub[(size_t)p * R_ + o] = f2bf(au);
}

// ---------------------------------------------------------------- fused act+down (MFMA)
// grid (16, G, DKZ_). Per 64-pair tile, loop 4x 64-col chunks of this kz's
// 256-col DFF slice: MFMA gate/up -> silu*mul -> bf16 act tile in LDS
// (C-layout write, A-layout read, own-wave rows only) -> MFMA acc into xd
// partial. act never touches HBM.
__global__ __launch_bounds__(256) void k_fused_ad(const unsigned short* __restrict__ xgb,
                                                  const unsigned short* __restrict__ xub,
                                                  const unsigned short* __restrict__ uoutT_g,
                                                  const unsigned short* __restrict__ uoutT_u,
                                                  const unsigned short* __restrict__ uinT_d,
                                                  const int* __restrict__ off,
                                                  float* __restrict__ xdp) {
  int g = blockIdx.y;
  int kz = blockIdx.z;
  int p0 = off[g * E_];
  int pend = off[g * E_ + E_];
  int ntiles = (pend - p0 + 63) >> 6;
  __shared__ short Ag[64 * LP_], Au[64 * LP_];
  __shared__ short Bg[64 * LP_], Bu[64 * LP_], Bd[64 * LP_];
  __shared__ short Pt[64 * LP_];
  int tid = threadIdx.x, lane = tid & 63, ms = (tid >> 6) * 16;
  int lm = lane & 15, lq = (lane >> 4) * 4;
  for (int tile = blockIdx.x; tile < ntiles; tile += gridDim.x) {
    int pbase = p0 + tile * 64;
    int rv = pend - pbase; if (rv > 64) rv = 64;
    stage_tile_guard(Ag, xgb + (size_t)pbase * R_, R_, rv, tid);
    stage_tile_guard(Au, xub + (size_t)pbase * R_, R_, rv, tid);
    f32x4 accd[4] = {};
#pragma unroll
    for (int c4 = 0; c4 < 4; ++c4) {
      int cc = kz * (DFF_ / DKZ_) + c4 * 64;
      stage_tile(Bg, uoutT_g + ((size_t)g * DFF_ + cc) * R_, R_, tid);
      stage_tile(Bu, uoutT_u + ((size_t)g * DFF_ + cc) * R_, R_, tid);
      stage_tile(Bd, uinT_d + (size_t)g * 64 * 1024 + cc, 1024, tid);
      __syncthreads();
      f32x4 accg[4] = {}, accu[4] = {};
      mma_strip(Ag, Bg, ms, lane, accg);
      mma_strip(Au, Bu, ms, lane, accu);
      // silu(gate)*up -> bf16 act tile rows [ms,ms+16) (own wave only)
#pragma unroll
      for (int nt = 0; nt < 4; ++nt)
#pragma unroll
        for (int r = 0; r < 4; ++r) {
          float gv = accg[nt][r];
          float av = gv / (1.f + expf(-gv)) * accu[nt][r];
          Pt[(ms + lq + r) * LP_ + nt * 16 + lm] = (short)f2bf(av);
        }
      // down-mma reads only own-wave rows of Pt (+ Bd staged above)
      mma_strip(Pt, Bd, ms, lane, accd);
      __syncthreads();
    }
#pragma unroll
    for (int nt = 0; nt < 4; ++nt)
#pragma unroll
      for (int r = 0; r < 4; ++r) {
        int p = pbase + ms + lq + r;
        if (p < pend) xdp[((size_t)kz * F_ + p) * R_ + nt * 16 + lm] = accd[nt][r];
      }
    __syncthreads();
  }
}

// ---------------------------------------------------------------- fold + down core (fp32) -> bf16
__global__ __launch_bounds__(256) void k_core_down(const float* __restrict__ xdp,
                                                   const float* __restrict__ core_d,
                                                   const int* __restrict__ se,
                                                   unsigned short* __restrict__ xd2b) {
  int pl = threadIdx.x >> 6;
  int o = threadIdx.x & 63;
  int p = blockIdx.x * 4 + pl;
  int e = se[p];
  __shared__ float rg[4][64];
  float s = 0.f;
#pragma unroll
  for (int kz = 0; kz < DKZ_; ++kz) s += xdp[((size_t)kz * F_ + p) * R_ + o];
  rg[pl][o] = s;
  __syncthreads();
  const float* cd = core_d + (size_t)e * R_ * R_;
  float a = 0.f;
#pragma unroll 8
  for (int r = 0; r < R_; ++r) a = fmaf(rg[pl][r], cd[r * R_ + o], a);
  xd2b[(size_t)p * R_ + o] = f2bf(a);
}

// ---------------------------------------------------------------- outf (MFMA) + gather via atomics
// grid (16, G, D/64). out[t] += w[p] * (xd2[p] @ uout_down[g]) directly.
__global__ __launch_bounds__(256) void k_outf_atomic(const unsigned short* __restrict__ xd2b,
                                                     const unsigned short* __restrict__ uoutT_d,
                                                     const int* __restrict__ off,
                                                     const float* __restrict__ sw,
                                                     const int* __restrict__ stok,
                                                     float* __restrict__ out) {
  int g = blockIdx.y;
  int p0 = off[g * E_];
  int pend = off[g * E_ + E_];
  int ntiles = (pend - p0 + 63) >> 6;
  int c0 = blockIdx.z * 64;
  __shared__ short As[64 * LP_], Bs[64 * LP_];
  int tid = threadIdx.x, lane = tid & 63, ms = (tid >> 6) * 16;
  int lm = lane & 15, lq = (lane >> 4) * 4;
  for (int tile = blockIdx.x; tile < ntiles; tile += gridDim.x) {
    int pbase = p0 + tile * 64;
    int rv = pend - pbase; if (rv > 64) rv = 64;
    stage_tile_guard(As, xd2b + (size_t)pbase * R_, R_, rv, tid);
    stage_tile(Bs, uoutT_d + ((size_t)g * D_ + c0) * R_, R_, tid);
    __syncthreads();
    f32x4 acc[4] = {};
    mma_strip(As, Bs, ms, lane, acc);
#pragma unroll
    for (int r = 0; r < 4; ++r) {
      int p = pbase + ms + lq + r;
      if (p < pend) {
        float wv = sw[p];
        int t = stok[p];
#pragma unroll
        for (int nt = 0; nt < 4; ++nt)
          atomicAdd(&out[(size_t)t * D_ + c0 + nt * 16 + lm], acc[nt][r] * wv);
      }
    }
    __syncthreads();
  }
}

// ================================================================ launch
extern "C" void kernel_launch(void* const* d_in, const int* in_sizes, int n_in,
                              void* d_out, int out_size, void* d_ws, size_t ws_size,
                              hipStream_t stream) {
  const float* x = (const float*)d_in[0];
  const float* Wg = (const float*)d_in[1];
  const float* uin_gate = (const float*)d_in[2];
  const float* core_gate = (const float*)d_in[3];
  const float* uout_gate = (const float*)d_in[4];
  const float* uin_up = (const float*)d_in[5];
  const float* core_up = (const float*)d_in[6];
  const float* uout_up = (const float*)d_in[7];
  const float* uin_down = (const float*)d_in[8];
  const float* core_down = (const float*)d_in[9];
  const float* uout_down = (const float*)d_in[10];
  float* out = (float*)d_out;

  char* ws = (char*)d_ws;
  size_t o = 0;
  auto alloc = [&](size_t bytes) { size_t r = o; o = (o + bytes + 255) & ~(size_t)255; return r; };
  size_t o_lp = alloc((size_t)LKZ_ * T_ * NEXP_ * 4);           // 8 MB
  size_t o_sel = alloc(F_ * 4);
  size_t o_wsm = alloc(F_ * 4);
  size_t o_cnt = alloc(NEXP_ * 4);
  size_t o_cur = alloc(NEXP_ * 4);
  size_t o_off = alloc((NEXP_ + 1) * 4);
  size_t o_stok = alloc(F_ * 4);
  size_t o_se = alloc(F_ * 4);
  size_t o_sw = alloc(F_ * 4);
  size_t o_xb = alloc((size_t)T_ * D_ * 2);                     // 2 MB
  size_t o_uinT_g = alloc((size_t)G_ * 64 * 1024 * 2);          // 1 MB each
  size_t o_uinT_u = alloc((size_t)G_ * 64 * 1024 * 2);
  size_t o_uinT_d = alloc((size_t)G_ * 64 * 1024 * 2);
  size_t o_uoutT_g = alloc((size_t)G_ * 1024 * 64 * 2);
  size_t o_uoutT_u = alloc((size_t)G_ * 1024 * 64 * 2);
  size_t o_uoutT_d = alloc((size_t)G_ * 1024 * 64 * 2);
  size_t o_xgb = alloc((size_t)F_ * R_ * 2);                    // 1 MB
  size_t o_xub = alloc((size_t)F_ * R_ * 2);
  size_t o_xd2b = alloc((size_t)F_ * R_ * 2);
  size_t o_pgp = alloc((size_t)PKZ_ * G_ * T_ * R_ * 4);        // 4 MB
  size_t o_pup = alloc((size_t)PKZ_ * G_ * T_ * R_ * 4);        // 4 MB
  size_t o_xdp = alloc((size_t)DKZ_ * F_ * R_ * 4);             // 8 MB
  (void)ws_size;

  float* lp = (float*)(ws + o_lp);
  int* sel = (int*)(ws + o_sel);
  float* wsm = (float*)(ws + o_wsm);
  int* cnt = (int*)(ws + o_cnt);
  int* cur = (int*)(ws + o_cur);
  int* off = (int*)(ws + o_off);
  int* stok = (int*)(ws + o_stok);
  int* se = (int*)(ws + o_se);
  float* sw = (float*)(ws + o_sw);
  unsigned short* xb = (unsigned short*)(ws + o_xb);
  unsigned short* uinT_g = (unsigned short*)(ws + o_uinT_g);
  unsigned short* uinT_u = (unsigned short*)(ws + o_uinT_u);
  unsigned short* uinT_d = (unsigned short*)(ws + o_uinT_d);
  unsigned short* uoutT_g = (unsigned short*)(ws + o_uoutT_g);
  unsigned short* uoutT_u = (unsigned short*)(ws + o_uoutT_u);
  unsigned short* uoutT_d = (unsigned short*)(ws + o_uoutT_d);
  unsigned short* xgb = (unsigned short*)(ws + o_xgb);
  unsigned short* xub = (unsigned short*)(ws + o_xub);
  unsigned short* xd2b = (unsigned short*)(ws + o_xd2b);
  float* pgp = (float*)(ws + o_pgp);
  float* pup = (float*)(ws + o_pup);
  float* xdp = (float*)(ws + o_xdp);

  hipMemsetAsync(out, 0, (size_t)T_ * D_ * 4, stream);  // atomic accumulate target

  k_prep<<<dim3(16, G_, 7), 256, 0, stream>>>(x, uin_gate, uin_up, uin_down,
                                              uout_gate, uout_up, uout_down, xb,
                                              uinT_g, uinT_u, uinT_d,
                                              uoutT_g, uoutT_u, uoutT_d, cnt, cur);
  k_logits<<<dim3(T_ / LTB_, LKZ_), 256, 0, stream>>>(x, Wg, lp);
  k_topk<<<T_ / 4, 256, 0, stream>>>(lp, sel, wsm, cnt);
  k_sortscan<<<1, 256, 0, stream>>>(cnt, sel, wsm, off, stok, se, sw);
  k_pre_mfma<<<dim3(T_ / 64, G_, 2 * PKZ_), 256, 0, stream>>>(xb, uinT_g, uinT_u, pgp, pup);
  k_core_gu<<<F_ / 4, 256, 0, stream>>>(pgp, pup, core_gate, core_up, stok, se, xgb, xub);
  k_fused_ad<<<dim3(16, G_, DKZ_), 256, 0, stream>>>(xgb, xub, uoutT_g, uoutT_u, uinT_d, off, xdp);
  k_core_down<<<F_ / 4, 256, 0, stream>>>(xdp, core_down, se, xd2b);
  k_outf_atomic<<<dim3(16, G_, D_ / 64), 256, 0, stream>>>(xd2b, uoutT_d, off, sw, stok, out);
}

// Round 7
// 225.626 us; speedup vs baseline: 1.2369x; 1.1285x over previous
//
#include <hip/hip_runtime.h>
#include <hip/hip_bf16.h>
#include <math.h>

// Tucker MoE: T=1024, D=1024, DFF=1024, R=64, G=8, E=32, NEXP=256, K=8, F=8192
// Round 7: de-atomize the output path (back to outf store + ipos gather, the
// R3-proven fastest ending) while keeping the good consolidations:
//  L1 k_prep_logits : casts/transposes + cnt zero  ||  router logits (fp32)
//  L2 k_pre_topk    : pre MFMA (split-K 2)         ||  top-k + softmax
//  L3 k_sortscan    : scan + scatter + ipos, one 1024-thread block
//  L4 k_core_gu     : fold pre partials + gate/up Tucker core (fp32) -> bf16
//  L5 k_fused_ad    : act(gate/up MFMA + silu*mul in LDS) fused with down MFMA
//  L6 k_core_down   : fold xd partials + down core (fp32) -> bf16
//  L7 k_outf_mfma   : w[p]*(xd2 @ uout_down[g]) -> outf (plain stores)
//  L8 k_gather      : out[t] = sum_k outf[ipos[t*8+k]]
// 8 dispatches, no memsets, no global atomics on the output path.

#define T_ 1024
#define D_ 1024
#define DFF_ 1024
#define R_ 64
#define G_ 8
#define E_ 32
#define NEXP_ 256
#define K_ 8
#define F_ 8192
#define LKZ_ 8   // router split-K (chunks of 128)
#define LTB_ 8   // router tokens per block
#define PKZ_ 2   // k_pre split-K
#define DKZ_ 4   // down split-K (chunks of 256 over DFF)
#define LP_ 72   // LDS tile pitch in bf16 elems (16B rows, 2-way bank alias = free)

typedef short bf16x8 __attribute__((ext_vector_type(8)));
typedef float f32x4 __attribute__((ext_vector_type(4)));

__device__ __forceinline__ unsigned short f2bf(float f) {
  unsigned int u = __float_as_uint(f);
  u += 0x7fffu + ((u >> 16) & 1u);  // RNE (finite inputs)
  return (unsigned short)(u >> 16);
}

__device__ __forceinline__ void stage_tile(short* dst, const unsigned short* src,
                                           int gp, int tid) {
  for (int idx = tid; idx < 512; idx += 256) {
    int r = idx >> 3, c8 = (idx & 7) << 3;
    *(uint4*)&dst[r * LP_ + c8] = *(const uint4*)&src[(size_t)r * gp + c8];
  }
}

__device__ __forceinline__ void stage_tile_guard(short* dst, const unsigned short* src,
                                                 int gp, int rows_valid, int tid) {
  for (int idx = tid; idx < 512; idx += 256) {
    int r = idx >> 3, c8 = (idx & 7) << 3;
    uint4 v = make_uint4(0u, 0u, 0u, 0u);
    if (r < rows_valid) v = *(const uint4*)&src[(size_t)r * gp + c8];
    *(uint4*)&dst[r * LP_ + c8] = v;
  }
}

// Wave computes a 16x64 strip (rows [ms,ms+16)) over K=64 from LDS tiles
// As (rows=m, k-contig) and Bs (rows=n, k-contig; i.e. B^T).
__device__ __forceinline__ void mma_strip(const short* As, const short* Bs,
                                          int ms, int lane, f32x4* acc) {
  int lm = lane & 15;
  int lk = (lane >> 4) << 3;
#pragma unroll
  for (int kc = 0; kc < 64; kc += 32) {
    bf16x8 a = *(const bf16x8*)&As[(ms + lm) * LP_ + kc + lk];
#pragma unroll
    for (int nt = 0; nt < 4; ++nt) {
      bf16x8 b = *(const bf16x8*)&Bs[(nt * 16 + lm) * LP_ + kc + lk];
      acc[nt] = __builtin_amdgcn_mfma_f32_16x16x32_bf16(a, b, acc[nt], 0, 0, 0);
    }
  }
}

// ---------------------------------------------------------------- L1: prep || logits
// 1D grid of 1920 blocks: b<896 = prep roles (id=b>>7: 0..5 weight cast+T,
// 6 = x cast + cnt zero); b>=896 = router logits split-K (1024 blocks).
__global__ __launch_bounds__(256) void k_prep_logits(
    const float* __restrict__ x, const float* __restrict__ Wg,
    const float* __restrict__ s0, const float* __restrict__ s1,
    const float* __restrict__ s2, const float* __restrict__ s3,
    const float* __restrict__ s4, const float* __restrict__ s5,
    unsigned short* __restrict__ xb,
    unsigned short* __restrict__ d0, unsigned short* __restrict__ d1,
    unsigned short* __restrict__ d2, unsigned short* __restrict__ d3,
    unsigned short* __restrict__ d4, unsigned short* __restrict__ d5,
    int* __restrict__ cnt, float* __restrict__ lp) {
  __shared__ float shbuf[64 * 65];  // prep: ts[64][65]; logits: xs[8][128]
  int b = blockIdx.x;
  if (b < 896) {
    int id = b >> 7, rem = b & 127, g = rem >> 4, tile = rem & 15;
    if (id == 6) {
      size_t base = ((size_t)g * 16 + tile) * 8192;
      for (int i = threadIdx.x; i < 2048; i += 256) {
        size_t idx = base + (size_t)i * 4;
        float4 v = *(const float4*)&x[idx];
        xb[idx + 0] = f2bf(v.x);
        xb[idx + 1] = f2bf(v.y);
        xb[idx + 2] = f2bf(v.z);
        xb[idx + 3] = f2bf(v.w);
      }
      if (g == 0 && tile == 0) cnt[threadIdx.x] = 0;
      return;
    }
    const float* src = id == 0 ? s0 : id == 1 ? s1 : id == 2 ? s2 : id == 3 ? s3 : id == 4 ? s4 : s5;
    unsigned short* dst = id == 0 ? d0 : id == 1 ? d1 : id == 2 ? d2 : id == 3 ? d3 : id == 4 ? d4 : d5;
    if (id < 3) {
      // uin*: src [g][1024][64] -> dst [g][64][1024]
      int r0 = tile * 64;
      for (int idx = threadIdx.x; idx < 4096; idx += 256) {
        int r = idx >> 6, c = idx & 63;
        shbuf[r * 65 + c] = src[((size_t)g * 1024 + r0 + r) * 64 + c];
      }
      __syncthreads();
      for (int idx = threadIdx.x; idx < 4096; idx += 256) {
        int c = idx >> 6, r = idx & 63;
        dst[((size_t)g * 64 + c) * 1024 + r0 + r] = f2bf(shbuf[r * 65 + c]);
      }
    } else {
      // uout*: src [g][64][1024] -> dst [g][1024][64]
      int c0 = tile * 64;
      for (int idx = threadIdx.x; idx < 4096; idx += 256) {
        int r = idx >> 6, c = idx & 63;
        shbuf[r * 65 + c] = src[((size_t)g * 64 + r) * 1024 + c0 + c];
      }
      __syncthreads();
      for (int idx = threadIdx.x; idx < 4096; idx += 256) {
        int c = idx >> 6, r = idx & 63;
        dst[((size_t)g * 1024 + c0 + c) * 64 + r] = f2bf(shbuf[r * 65 + c]);
      }
    }
    return;
  }
  // ---- router logits: lp[z][t][e], 8 tokens/block, K-chunk of 128
  int lb = b - 896;
  int t0 = (lb & 127) * LTB_;
  int z = lb >> 7;
  int e = threadIdx.x;
  float* xs = shbuf;  // [8][128]
  float a[LTB_] = {};
  int dc = z * 128;
  {
    int idx = threadIdx.x * 4;  // 256 thr x float4 = the whole 8x128 tile
    int tl = idx >> 7, d = idx & 127;
    *(float4*)&xs[tl * 128 + d] = *(const float4*)&x[(size_t)(t0 + tl) * D_ + dc + d];
  }
  __syncthreads();
#pragma unroll 8
  for (int d2 = 0; d2 < 128; ++d2) {
    float wv = Wg[(size_t)(dc + d2) * NEXP_ + e];
#pragma unroll
    for (int j = 0; j < LTB_; ++j) a[j] = fmaf(xs[j * 128 + d2], wv, a[j]);
  }
  size_t base = (size_t)z * T_ * NEXP_;
#pragma unroll
  for (int j = 0; j < LTB_; ++j)
    lp[base + (size_t)(t0 + j) * NEXP_ + e] = a[j];
}

// ---------------------------------------------------------------- L2: pre MFMA || topk
// 1D grid of 768 blocks: b<512 = pre (tile=b&15, g=(b>>4)&7, gu/kz from b>>7);
// b>=512 = topk over 4 tokens/block.
__global__ __launch_bounds__(256) void k_pre_topk(
    const unsigned short* __restrict__ xb,
    const unsigned short* __restrict__ uinT_g, const unsigned short* __restrict__ uinT_u,
    const float* __restrict__ lp,
    float* __restrict__ Pgp, float* __restrict__ Pup,
    int* __restrict__ sel, float* __restrict__ wsm, int* __restrict__ cnt) {
  __shared__ short sh2[2 * 64 * LP_];
  int b = blockIdx.x;
  if (b < 512) {
    int tile = b & 15, g = (b >> 4) & 7, zz = b >> 7;
    int gu = zz >> 1, kz = zz & 1;
    const unsigned short* U = gu ? uinT_u : uinT_g;  // [G][64(r)][1024(d)]
    float* P = gu ? Pup : Pgp;
    int t0 = tile * 64;
    short* As = sh2;
    short* Bs = sh2 + 64 * LP_;
    int tid = threadIdx.x, lane = tid & 63, ms = (tid >> 6) * 16;
    f32x4 acc[4] = {};
    int dlo = kz * (D_ / PKZ_);
    for (int dc = dlo; dc < dlo + D_ / PKZ_; dc += 64) {
      stage_tile(As, xb + (size_t)t0 * D_ + dc, D_, tid);
      stage_tile(Bs, U + (size_t)g * 64 * 1024 + dc, 1024, tid);
      __syncthreads();
      mma_strip(As, Bs, ms, lane, acc);
      __syncthreads();
    }
    int lm = lane & 15, lq = (lane >> 4) * 4;
#pragma unroll
    for (int nt = 0; nt < 4; ++nt)
#pragma unroll
      for (int r = 0; r < 4; ++r)
        P[((size_t)(kz * G_ + g) * T_ + t0 + ms + lq + r) * R_ + nt * 16 + lm] = acc[nt][r];
    return;
  }
  // ---- topk: one wave per token, folds the LKZ_ logits partials on load
  int tb = b - 512;
  int wave = threadIdx.x >> 6;
  int lane = threadIdx.x & 63;
  int t = tb * 4 + wave;
  float v[4];
  int idx[4];
#pragma unroll
  for (int j = 0; j < 4; ++j) {
    idx[j] = lane + 64 * j;
    float s = 0.f;
#pragma unroll
    for (int z = 0; z < LKZ_; ++z)
      s += lp[(size_t)z * T_ * NEXP_ + (size_t)t * NEXP_ + idx[j]];
    v[j] = s;
  }
  float topv[K_];
  int topi[K_];
#pragma unroll
  for (int k = 0; k < K_; ++k) {
    float bv = v[0];
    int bi = idx[0];
#pragma unroll
    for (int j = 1; j < 4; ++j)
      if (v[j] > bv || (v[j] == bv && idx[j] < bi)) { bv = v[j]; bi = idx[j]; }
#pragma unroll
    for (int off = 32; off > 0; off >>= 1) {
      float ov = __shfl_xor(bv, off);
      int oi = __shfl_xor(bi, off);
      if (ov > bv || (ov == bv && oi < bi)) { bv = ov; bi = oi; }
    }
    topv[k] = bv;
    topi[k] = bi;
#pragma unroll
    for (int j = 0; j < 4; ++j)
      if (idx[j] == bi) v[j] = -INFINITY;
  }
  float m = topv[0];
  float ev[K_];
  float s = 0.f;
#pragma unroll
  for (int k = 0; k < K_; ++k) { ev[k] = expf(topv[k] - m); s += ev[k]; }
  float inv = 1.f / s;
  if (lane < K_) {
    sel[t * K_ + lane] = topi[lane];
    wsm[t * K_ + lane] = ev[lane] * inv;
    atomicAdd(&cnt[topi[lane]], 1);
  }
}

// ---------------------------------------------------------------- L3: scan + scatter + ipos (1 block x 1024)
__global__ __launch_bounds__(1024) void k_sortscan(const int* __restrict__ cnt,
                                                   const int* __restrict__ sel,
                                                   const float* __restrict__ wsm,
                                                   int* __restrict__ off,
                                                   int* __restrict__ stok,
                                                   int* __restrict__ se,
                                                   float* __restrict__ sw,
                                                   int* __restrict__ ipos) {
  __shared__ int s[NEXP_];
  __shared__ int offl[NEXP_];
  __shared__ int curl[NEXP_];
  int i = threadIdx.x;
  if (i < NEXP_) s[i] = cnt[i];
  __syncthreads();
  for (int d = 1; d < NEXP_; d <<= 1) {
    int v = 0;
    if (i < NEXP_ && i >= d) v = s[i - d];
    __syncthreads();
    if (i < NEXP_) s[i] += v;
    __syncthreads();
  }
  if (i < NEXP_) {
    offl[i] = s[i] - cnt[i];  // exclusive
    curl[i] = 0;
    off[i + 1] = s[i];
    if (i == 0) off[0] = 0;
  }
  __syncthreads();
  for (int f = i; f < F_; f += 1024) {
    int e = sel[f];
    int p = offl[e] + atomicAdd(&curl[e], 1);
    stok[p] = f >> 3;
    se[p] = e;
    sw[p] = wsm[f];
    ipos[f] = p;
  }
}

// ---------------------------------------------------------------- L4: fold pre + gate/up core (fp32) -> bf16
__global__ __launch_bounds__(256) void k_core_gu(const float* __restrict__ Pgp,
                                                 const float* __restrict__ Pup,
                                                 const float* __restrict__ core_g,
                                                 const float* __restrict__ core_u,
                                                 const int* __restrict__ stok,
                                                 const int* __restrict__ se,
                                                 unsigned short* __restrict__ xgb,
                                                 unsigned short* __restrict__ xub) {
  int pl = threadIdx.x >> 6;
  int o = threadIdx.x & 63;
  int p = blockIdx.x * 4 + pl;
  int e = se[p];
  int t = stok[p];
  int g = e >> 5;
  __shared__ float rg[4][64], ru[4][64];
  float sg = 0.f, su = 0.f;
#pragma unroll
  for (int kz = 0; kz < PKZ_; ++kz) {
    sg += Pgp[((size_t)(kz * G_ + g) * T_ + t) * R_ + o];
    su += Pup[((size_t)(kz * G_ + g) * T_ + t) * R_ + o];
  }
  rg[pl][o] = sg;
  ru[pl][o] = su;
  __syncthreads();
  const float* cg = core_g + (size_t)e * R_ * R_;
  const float* cu = core_u + (size_t)e * R_ * R_;
  float ag = 0.f, au = 0.f;
#pragma unroll 8
  for (int r = 0; r < R_; ++r) {
    ag = fmaf(rg[pl][r], cg[r * R_ + o], ag);
    au = fmaf(ru[pl][r], cu[r * R_ + o], au);
  }
  xgb[(size_t)p * R_ + o] = f2bf(ag);
  xub[(size_t)p * R_ + o] = f2bf(au);
}

// ---------------------------------------------------------------- L5: fused act+down (MFMA)
__global__ __launch_bounds__(256) void k_fused_ad(const unsigned short* __restrict__ xgb,
                                                  const unsigned short* __restrict__ xub,
                                                  const unsigned short* __restrict__ uoutT_g,
                                                  const unsigned short* __restrict__ uoutT_u,
                                                  const unsigned short* __restrict__ uinT_d,
                                                  const int* __restrict__ off,
                                                  float* __restrict__ xdp) {
  int g = blockIdx.y;
  int kz = blockIdx.z;
  int p0 = off[g * E_];
  int pend = off[g * E_ + E_];
  int ntiles = (pend - p0 + 63) >> 6;
  __shared__ short Ag[64 * LP_], Au[64 * LP_];
  __shared__ short Bg[64 * LP_], Bu[64 * LP_], Bd[64 * LP_];
  __shared__ short Pt[64 * LP_];
  int tid = threadIdx.x, lane = tid & 63, ms = (tid >> 6) * 16;
  int lm = lane & 15, lq = (lane >> 4) * 4;
  for (int tile = blockIdx.x; tile < ntiles; tile += gridDim.x) {
    int pbase = p0 + tile * 64;
    int rv = pend - pbase; if (rv > 64) rv = 64;
    stage_tile_guard(Ag, xgb + (size_t)pbase * R_, R_, rv, tid);
    stage_tile_guard(Au, xub + (size_t)pbase * R_, R_, rv, tid);
    f32x4 accd[4] = {};
#pragma unroll
    for (int c4 = 0; c4 < 4; ++c4) {
      int cc = kz * (DFF_ / DKZ_) + c4 * 64;
      stage_tile(Bg, uoutT_g + ((size_t)g * DFF_ + cc) * R_, R_, tid);
      stage_tile(Bu, uoutT_u + ((size_t)g * DFF_ + cc) * R_, R_, tid);
      stage_tile(Bd, uinT_d + (size_t)g * 64 * 1024 + cc, 1024, tid);
      __syncthreads();
      f32x4 accg[4] = {}, accu[4] = {};
      mma_strip(Ag, Bg, ms, lane, accg);
      mma_strip(Au, Bu, ms, lane, accu);
#pragma unroll
      for (int nt = 0; nt < 4; ++nt)
#pragma unroll
        for (int r = 0; r < 4; ++r) {
          float gv = accg[nt][r];
          float av = gv / (1.f + expf(-gv)) * accu[nt][r];
          Pt[(ms + lq + r) * LP_ + nt * 16 + lm] = (short)f2bf(av);
        }
      mma_strip(Pt, Bd, ms, lane, accd);  // reads only own-wave rows of Pt
      __syncthreads();
    }
#pragma unroll
    for (int nt = 0; nt < 4; ++nt)
#pragma unroll
      for (int r = 0; r < 4; ++r) {
        int p = pbase + ms + lq + r;
        if (p < pend) xdp[((size_t)kz * F_ + p) * R_ + nt * 16 + lm] = accd[nt][r];
      }
    __syncthreads();
  }
}

// ---------------------------------------------------------------- L6: fold + down core (fp32) -> bf16
__global__ __launch_bounds__(256) void k_core_down(const float* __restrict__ xdp,
                                                   const float* __restrict__ core_d,
                                                   const int* __restrict__ se,
                                                   unsigned short* __restrict__ xd2b) {
  int pl = threadIdx.x >> 6;
  int o = threadIdx.x & 63;
  int p = blockIdx.x * 4 + pl;
  int e = se[p];
  __shared__ float rg[4][64];
  float s = 0.f;
#pragma unroll
  for (int kz = 0; kz < DKZ_; ++kz) s += xdp[((size_t)kz * F_ + p) * R_ + o];
  rg[pl][o] = s;
  __syncthreads();
  const float* cd = core_d + (size_t)e * R_ * R_;
  float a = 0.f;
#pragma unroll 8
  for (int r = 0; r < R_; ++r) a = fmaf(rg[pl][r], cd[r * R_ + o], a);
  xd2b[(size_t)p * R_ + o] = f2bf(a);
}

// ---------------------------------------------------------------- L7: outf = w[p]*(xd2 @ uout_down[g])
__global__ __launch_bounds__(256) void k_outf_mfma(const unsigned short* __restrict__ xd2b,
                                                   const unsigned short* __restrict__ uoutT_d,
                                                   const int* __restrict__ off,
                                                   const float* __restrict__ sw,
                                                   float* __restrict__ outf) {
  int g = blockIdx.y;
  int p0 = off[g * E_];
  int pend = off[g * E_ + E_];
  int ntiles = (pend - p0 + 63) >> 6;
  int c0 = blockIdx.z * 64;
  __shared__ short As[64 * LP_], Bs[64 * LP_];
  __shared__ float Os[64 * 68];
  int tid = threadIdx.x, lane = tid & 63, ms = (tid >> 6) * 16;
  int lm = lane & 15, lq = (lane >> 4) * 4;
  for (int tile = blockIdx.x; tile < ntiles; tile += gridDim.x) {
    int pbase = p0 + tile * 64;
    int rv = pend - pbase; if (rv > 64) rv = 64;
    stage_tile_guard(As, xd2b + (size_t)pbase * R_, R_, rv, tid);
    stage_tile(Bs, uoutT_d + ((size_t)g * D_ + c0) * R_, R_, tid);
    __syncthreads();
    f32x4 acc[4] = {};
    mma_strip(As, Bs, ms, lane, acc);
    float wv[4];
#pragma unroll
    for (int r = 0; r < 4; ++r) {
      int p = pbase + ms + lq + r;
      wv[r] = (p < pend) ? sw[p] : 0.f;
    }
#pragma unroll
    for (int nt = 0; nt < 4; ++nt)
#pragma unroll
      for (int r = 0; r < 4; ++r)
        Os[(ms + lq + r) * 68 + nt * 16 + lm] = acc[nt][r] * wv[r];
    __syncthreads();
    for (int idx = tid; idx < 1024; idx += 256) {
      int r = idx >> 4, c4 = (idx & 15) << 2;
      if (r < rv)
        *(float4*)&outf[(size_t)(pbase + r) * D_ + c0 + c4] = *(const float4*)&Os[r * 68 + c4];
    }
    __syncthreads();
  }
}

// ---------------------------------------------------------------- L8: gather: out[t] = sum_k outf[ipos[t*8+k]]
__global__ __launch_bounds__(256) void k_gather(const float* __restrict__ outf,
                                                const int* __restrict__ ipos,
                                                float* __restrict__ out) {
  int t = blockIdx.x;
  __shared__ int pos[K_];
  if (threadIdx.x < K_) pos[threadIdx.x] = ipos[t * K_ + threadIdx.x];
  __syncthreads();
  int c = threadIdx.x * 4;
  float4 s = make_float4(0.f, 0.f, 0.f, 0.f);
#pragma unroll
  for (int k = 0; k < K_; ++k) {
    float4 v = *(const float4*)(outf + (size_t)pos[k] * D_ + c);
    s.x += v.x; s.y += v.y; s.z += v.z; s.w += v.w;
  }
  *(float4*)(out + (size_t)t * D_ + c) = s;
}

// ================================================================ launch
extern "C" void kernel_launch(void* const* d_in, const int* in_sizes, int n_in,
                              void* d_out, int out_size, void* d_ws, size_t ws_size,
                              hipStream_t stream) {
  const float* x = (const float*)d_in[0];
  const float* Wg = (const float*)d_in[1];
  const float* uin_gate = (const float*)d_in[2];
  const float* core_gate = (const float*)d_in[3];
  const float* uout_gate = (const float*)d_in[4];
  const float* uin_up = (const float*)d_in[5];
  const float* core_up = (const float*)d_in[6];
  const float* uout_up = (const float*)d_in[7];
  const float* uin_down = (const float*)d_in[8];
  const float* core_down = (const float*)d_in[9];
  const float* uout_down = (const float*)d_in[10];
  float* out = (float*)d_out;

  char* ws = (char*)d_ws;
  size_t o = 0;
  auto alloc = [&](size_t bytes) { size_t r = o; o = (o + bytes + 255) & ~(size_t)255; return r; };
  size_t o_lp = alloc((size_t)LKZ_ * T_ * NEXP_ * 4);           // 8 MB
  size_t o_sel = alloc(F_ * 4);
  size_t o_wsm = alloc(F_ * 4);
  size_t o_cnt = alloc(NEXP_ * 4);
  size_t o_off = alloc((NEXP_ + 1) * 4);
  size_t o_stok = alloc(F_ * 4);
  size_t o_se = alloc(F_ * 4);
  size_t o_sw = alloc(F_ * 4);
  size_t o_ipos = alloc(F_ * 4);
  size_t o_xb = alloc((size_t)T_ * D_ * 2);                     // 2 MB
  size_t o_uinT_g = alloc((size_t)G_ * 64 * 1024 * 2);          // 1 MB each
  size_t o_uinT_u = alloc((size_t)G_ * 64 * 1024 * 2);
  size_t o_uinT_d = alloc((size_t)G_ * 64 * 1024 * 2);
  size_t o_uoutT_g = alloc((size_t)G_ * 1024 * 64 * 2);
  size_t o_uoutT_u = alloc((size_t)G_ * 1024 * 64 * 2);
  size_t o_uoutT_d = alloc((size_t)G_ * 1024 * 64 * 2);
  size_t o_xgb = alloc((size_t)F_ * R_ * 2);                    // 1 MB
  size_t o_xub = alloc((size_t)F_ * R_ * 2);
  size_t o_xd2b = alloc((size_t)F_ * R_ * 2);
  size_t o_pgp = alloc((size_t)PKZ_ * G_ * T_ * R_ * 4);        // 4 MB
  size_t o_pup = alloc((size_t)PKZ_ * G_ * T_ * R_ * 4);        // 4 MB
  size_t o_xdp = alloc((size_t)DKZ_ * F_ * R_ * 4);             // 8 MB
  size_t o_outf = alloc((size_t)F_ * D_ * 4);                   // 32 MB
  (void)ws_size;

  float* lp = (float*)(ws + o_lp);
  int* sel = (int*)(ws + o_sel);
  float* wsm = (float*)(ws + o_wsm);
  int* cnt = (int*)(ws + o_cnt);
  int* off = (int*)(ws + o_off);
  int* stok = (int*)(ws + o_stok);
  int* se = (int*)(ws + o_se);
  float* sw = (float*)(ws + o_sw);
  int* ipos = (int*)(ws + o_ipos);
  unsigned short* xb = (unsigned short*)(ws + o_xb);
  unsigned short* uinT_g = (unsigned short*)(ws + o_uinT_g);
  unsigned short* uinT_u = (unsigned short*)(ws + o_uinT_u);
  unsigned short* uinT_d = (unsigned short*)(ws + o_uinT_d);
  unsigned short* uoutT_g = (unsigned short*)(ws + o_uoutT_g);
  unsigned short* uoutT_u = (unsigned short*)(ws + o_uoutT_u);
  unsigned short* uoutT_d = (unsigned short*)(ws + o_uoutT_d);
  unsigned short* xgb = (unsigned short*)(ws + o_xgb);
  unsigned short* xub = (unsigned short*)(ws + o_xub);
  unsigned short* xd2b = (unsigned short*)(ws + o_xd2b);
  float* pgp = (float*)(ws + o_pgp);
  float* pup = (float*)(ws + o_pup);
  float* xdp = (float*)(ws + o_xdp);
  float* outf = (float*)(ws + o_outf);

  k_prep_logits<<<1920, 256, 0, stream>>>(x, Wg, uin_gate, uin_up, uin_down,
                                          uout_gate, uout_up, uout_down, xb,
                                          uinT_g, uinT_u, uinT_d,
                                          uoutT_g, uoutT_u, uoutT_d, cnt, lp);
  k_pre_topk<<<768, 256, 0, stream>>>(xb, uinT_g, uinT_u, lp, pgp, pup, sel, wsm, cnt);
  k_sortscan<<<1, 1024, 0, stream>>>(cnt, sel, wsm, off, stok, se, sw, ipos);
  k_core_gu<<<F_ / 4, 256, 0, stream>>>(pgp, pup, core_gate, core_up, stok, se, xgb, xub);
  k_fused_ad<<<dim3(16, G_, DKZ_), 256, 0, stream>>>(xgb, xub, uoutT_g, uoutT_u, uinT_d, off, xdp);
  k_core_down<<<F_ / 4, 256, 0, stream>>>(xdp, core_down, se, xd2b);
  k_outf_mfma<<<dim3(16, G_, D_ / 64), 256, 0, stream>>>(xd2b, uoutT_d, off, sw, outf);
  k_gather<<<T_, 256, 0, stream>>>(outf, ipos, out);
}

// Round 8
// 221.190 us; speedup vs baseline: 1.2617x; 1.0201x over previous
//
#include <hip/hip_runtime.h>
#include <hip/hip_bf16.h>
#include <math.h>

// Tucker MoE: T=1024, D=1024, DFF=1024, R=64, G=8, E=32, NEXP=256, K=8, F=8192
// Round 8: fold pair contributions BEFORE the final GEMM.
//   Y[t][g][r] = sum_{k: g_k=g} w_k * xd2[p_k][r]   (k_accY, tiny)
//   out = Y[1024,512] @ Uod2[512,1024]              (k_fin, dense bf16 MFMA)
// Deletes outf (32 MB write) + gather (32 MB read). L1-L6 identical to R7.
//  L1 k_prep_logits : casts/transposes (uout_down -> [d][g*64+r]) || logits
//  L2 k_pre_topk    : pre MFMA (split-K 2) || top-k + softmax
//  L3 k_sortscan    : scan + scatter + ipos, one 1024-thread block
//  L4 k_core_gu     : fold pre partials + gate/up core (fp32) -> bf16
//  L5 k_fused_ad    : act(gate/up MFMA + silu*mul in LDS) fused with down MFMA
//  L6 k_core_down   : fold xd partials + down core (fp32) -> bf16
//  L7 k_accY        : token-fold of weighted xd2 -> Y bf16 [T,512]
//  L8 k_fin         : dense out = Y @ Uod2 (256 blocks, no routing)

#define T_ 1024
#define D_ 1024
#define DFF_ 1024
#define R_ 64
#define G_ 8
#define E_ 32
#define NEXP_ 256
#define K_ 8
#define F_ 8192
#define LKZ_ 8   // router split-K (chunks of 128)
#define LTB_ 8   // router tokens per block
#define PKZ_ 2   // k_pre split-K
#define DKZ_ 4   // down split-K (chunks of 256 over DFF)
#define LP_ 72   // LDS tile pitch in bf16 elems (16B rows, 2-way bank alias = free)

typedef short bf16x8 __attribute__((ext_vector_type(8)));
typedef float f32x4 __attribute__((ext_vector_type(4)));

__device__ __forceinline__ unsigned short f2bf(float f) {
  unsigned int u = __float_as_uint(f);
  u += 0x7fffu + ((u >> 16) & 1u);  // RNE (finite inputs)
  return (unsigned short)(u >> 16);
}
__device__ __forceinline__ float bf2f(unsigned short h) {
  return __uint_as_float((unsigned int)h << 16);
}

__device__ __forceinline__ void stage_tile(short* dst, const unsigned short* src,
                                           int gp, int tid) {
  for (int idx = tid; idx < 512; idx += 256) {
    int r = idx >> 3, c8 = (idx & 7) << 3;
    *(uint4*)&dst[r * LP_ + c8] = *(const uint4*)&src[(size_t)r * gp + c8];
  }
}

__device__ __forceinline__ void stage_tile_guard(short* dst, const unsigned short* src,
                                                 int gp, int rows_valid, int tid) {
  for (int idx = tid; idx < 512; idx += 256) {
    int r = idx >> 3, c8 = (idx & 7) << 3;
    uint4 v = make_uint4(0u, 0u, 0u, 0u);
    if (r < rows_valid) v = *(const uint4*)&src[(size_t)r * gp + c8];
    *(uint4*)&dst[r * LP_ + c8] = v;
  }
}

// Wave computes a 16x64 strip (rows [ms,ms+16)) over K=64 from LDS tiles
// As (rows=m, k-contig) and Bs (rows=n, k-contig; i.e. B^T).
__device__ __forceinline__ void mma_strip(const short* As, const short* Bs,
                                          int ms, int lane, f32x4* acc) {
  int lm = lane & 15;
  int lk = (lane >> 4) << 3;
#pragma unroll
  for (int kc = 0; kc < 64; kc += 32) {
    bf16x8 a = *(const bf16x8*)&As[(ms + lm) * LP_ + kc + lk];
#pragma unroll
    for (int nt = 0; nt < 4; ++nt) {
      bf16x8 b = *(const bf16x8*)&Bs[(nt * 16 + lm) * LP_ + kc + lk];
      acc[nt] = __builtin_amdgcn_mfma_f32_16x16x32_bf16(a, b, acc[nt], 0, 0, 0);
    }
  }
}

// ---------------------------------------------------------------- L1: prep || logits
// 1D grid of 1920 blocks: b<896 = prep roles (id=b>>7: 0..4 as before,
// id 5 = uout_down -> Uod2T[d][g*64+r]; 6 = x cast + cnt zero);
// b>=896 = router logits split-K (1024 blocks).
__global__ __launch_bounds__(256) void k_prep_logits(
    const float* __restrict__ x, const float* __restrict__ Wg,
    const float* __restrict__ s0, const float* __restrict__ s1,
    const float* __restrict__ s2, const float* __restrict__ s3,
    const float* __restrict__ s4, const float* __restrict__ s5,
    unsigned short* __restrict__ xb,
    unsigned short* __restrict__ d0, unsigned short* __restrict__ d1,
    unsigned short* __restrict__ d2, unsigned short* __restrict__ d3,
    unsigned short* __restrict__ d4, unsigned short* __restrict__ d5,
    int* __restrict__ cnt, float* __restrict__ lp) {
  __shared__ float shbuf[64 * 65];  // prep: ts[64][65]; logits: xs[8][128]
  int b = blockIdx.x;
  if (b < 896) {
    int id = b >> 7, rem = b & 127, g = rem >> 4, tile = rem & 15;
    if (id == 6) {
      size_t base = ((size_t)g * 16 + tile) * 8192;
      for (int i = threadIdx.x; i < 2048; i += 256) {
        size_t idx = base + (size_t)i * 4;
        float4 v = *(const float4*)&x[idx];
        xb[idx + 0] = f2bf(v.x);
        xb[idx + 1] = f2bf(v.y);
        xb[idx + 2] = f2bf(v.z);
        xb[idx + 3] = f2bf(v.w);
      }
      if (g == 0 && tile == 0) cnt[threadIdx.x] = 0;
      return;
    }
    const float* src = id == 0 ? s0 : id == 1 ? s1 : id == 2 ? s2 : id == 3 ? s3 : id == 4 ? s4 : s5;
    unsigned short* dst = id == 0 ? d0 : id == 1 ? d1 : id == 2 ? d2 : id == 3 ? d3 : id == 4 ? d4 : d5;
    if (id < 3) {
      // uin*: src [g][1024][64] -> dst [g][64][1024]
      int r0 = tile * 64;
      for (int idx = threadIdx.x; idx < 4096; idx += 256) {
        int r = idx >> 6, c = idx & 63;
        shbuf[r * 65 + c] = src[((size_t)g * 1024 + r0 + r) * 64 + c];
      }
      __syncthreads();
      for (int idx = threadIdx.x; idx < 4096; idx += 256) {
        int c = idx >> 6, r = idx & 63;
        dst[((size_t)g * 64 + c) * 1024 + r0 + r] = f2bf(shbuf[r * 65 + c]);
      }
    } else {
      // uout*: src [g][64][1024]; id 3/4 -> [g][1024][64]; id 5 -> [d][g*64+r]
      int c0 = tile * 64;
      for (int idx = threadIdx.x; idx < 4096; idx += 256) {
        int r = idx >> 6, c = idx & 63;
        shbuf[r * 65 + c] = src[((size_t)g * 64 + r) * 1024 + c0 + c];
      }
      __syncthreads();
      if (id == 5) {
        for (int idx = threadIdx.x; idx < 4096; idx += 256) {
          int c = idx >> 6, r = idx & 63;
          dst[(size_t)(c0 + c) * 512 + g * 64 + r] = f2bf(shbuf[r * 65 + c]);
        }
      } else {
        for (int idx = threadIdx.x; idx < 4096; idx += 256) {
          int c = idx >> 6, r = idx & 63;
          dst[((size_t)g * 1024 + c0 + c) * 64 + r] = f2bf(shbuf[r * 65 + c]);
        }
      }
    }
    return;
  }
  // ---- router logits: lp[z][t][e], 8 tokens/block, K-chunk of 128
  int lb = b - 896;
  int t0 = (lb & 127) * LTB_;
  int z = lb >> 7;
  int e = threadIdx.x;
  float* xs = shbuf;  // [8][128]
  float a[LTB_] = {};
  int dc = z * 128;
  {
    int idx = threadIdx.x * 4;  // 256 thr x float4 = the whole 8x128 tile
    int tl = idx >> 7, d = idx & 127;
    *(float4*)&xs[tl * 128 + d] = *(const float4*)&x[(size_t)(t0 + tl) * D_ + dc + d];
  }
  __syncthreads();
#pragma unroll 8
  for (int d2 = 0; d2 < 128; ++d2) {
    float wv = Wg[(size_t)(dc + d2) * NEXP_ + e];
#pragma unroll
    for (int j = 0; j < LTB_; ++j) a[j] = fmaf(xs[j * 128 + d2], wv, a[j]);
  }
  size_t base = (size_t)z * T_ * NEXP_;
#pragma unroll
  for (int j = 0; j < LTB_; ++j)
    lp[base + (size_t)(t0 + j) * NEXP_ + e] = a[j];
}

// ---------------------------------------------------------------- L2: pre MFMA || topk
__global__ __launch_bounds__(256) void k_pre_topk(
    const unsigned short* __restrict__ xb,
    const unsigned short* __restrict__ uinT_g, const unsigned short* __restrict__ uinT_u,
    const float* __restrict__ lp,
    float* __restrict__ Pgp, float* __restrict__ Pup,
    int* __restrict__ sel, float* __restrict__ wsm, int* __restrict__ cnt) {
  __shared__ short sh2[2 * 64 * LP_];
  int b = blockIdx.x;
  if (b < 512) {
    int tile = b & 15, g = (b >> 4) & 7, zz = b >> 7;
    int gu = zz >> 1, kz = zz & 1;
    const unsigned short* U = gu ? uinT_u : uinT_g;  // [G][64(r)][1024(d)]
    float* P = gu ? Pup : Pgp;
    int t0 = tile * 64;
    short* As = sh2;
    short* Bs = sh2 + 64 * LP_;
    int tid = threadIdx.x, lane = tid & 63, ms = (tid >> 6) * 16;
    f32x4 acc[4] = {};
    int dlo = kz * (D_ / PKZ_);
    for (int dc = dlo; dc < dlo + D_ / PKZ_; dc += 64) {
      stage_tile(As, xb + (size_t)t0 * D_ + dc, D_, tid);
      stage_tile(Bs, U + (size_t)g * 64 * 1024 + dc, 1024, tid);
      __syncthreads();
      mma_strip(As, Bs, ms, lane, acc);
      __syncthreads();
    }
    int lm = lane & 15, lq = (lane >> 4) * 4;
#pragma unroll
    for (int nt = 0; nt < 4; ++nt)
#pragma unroll
      for (int r = 0; r < 4; ++r)
        P[((size_t)(kz * G_ + g) * T_ + t0 + ms + lq + r) * R_ + nt * 16 + lm] = acc[nt][r];
    return;
  }
  // ---- topk: one wave per token, folds the LKZ_ logits partials on load
  int tb = b - 512;
  int wave = threadIdx.x >> 6;
  int lane = threadIdx.x & 63;
  int t = tb * 4 + wave;
  float v[4];
  int idx[4];
#pragma unroll
  for (int j = 0; j < 4; ++j) {
    idx[j] = lane + 64 * j;
    float s = 0.f;
#pragma unroll
    for (int z = 0; z < LKZ_; ++z)
      s += lp[(size_t)z * T_ * NEXP_ + (size_t)t * NEXP_ + idx[j]];
    v[j] = s;
  }
  float topv[K_];
  int topi[K_];
#pragma unroll
  for (int k = 0; k < K_; ++k) {
    float bv = v[0];
    int bi = idx[0];
#pragma unroll
    for (int j = 1; j < 4; ++j)
      if (v[j] > bv || (v[j] == bv && idx[j] < bi)) { bv = v[j]; bi = idx[j]; }
#pragma unroll
    for (int off = 32; off > 0; off >>= 1) {
      float ov = __shfl_xor(bv, off);
      int oi = __shfl_xor(bi, off);
      if (ov > bv || (ov == bv && oi < bi)) { bv = ov; bi = oi; }
    }
    topv[k] = bv;
    topi[k] = bi;
#pragma unroll
    for (int j = 0; j < 4; ++j)
      if (idx[j] == bi) v[j] = -INFINITY;
  }
  float m = topv[0];
  float ev[K_];
  float s = 0.f;
#pragma unroll
  for (int k = 0; k < K_; ++k) { ev[k] = expf(topv[k] - m); s += ev[k]; }
  float inv = 1.f / s;
  if (lane < K_) {
    sel[t * K_ + lane] = topi[lane];
    wsm[t * K_ + lane] = ev[lane] * inv;
    atomicAdd(&cnt[topi[lane]], 1);
  }
}

// ---------------------------------------------------------------- L3: scan + scatter + ipos (1 block x 1024)
__global__ __launch_bounds__(1024) void k_sortscan(const int* __restrict__ cnt,
                                                   const int* __restrict__ sel,
                                                   const float* __restrict__ wsm,
                                                   int* __restrict__ off,
                                                   int* __restrict__ stok,
                                                   int* __restrict__ se,
                                                   float* __restrict__ sw,
                                                   int* __restrict__ ipos) {
  __shared__ int s[NEXP_];
  __shared__ int offl[NEXP_];
  __shared__ int curl[NEXP_];
  int i = threadIdx.x;
  if (i < NEXP_) s[i] = cnt[i];
  __syncthreads();
  for (int d = 1; d < NEXP_; d <<= 1) {
    int v = 0;
    if (i < NEXP_ && i >= d) v = s[i - d];
    __syncthreads();
    if (i < NEXP_) s[i] += v;
    __syncthreads();
  }
  if (i < NEXP_) {
    offl[i] = s[i] - cnt[i];  // exclusive
    curl[i] = 0;
    off[i + 1] = s[i];
    if (i == 0) off[0] = 0;
  }
  __syncthreads();
  for (int f = i; f < F_; f += 1024) {
    int e = sel[f];
    int p = offl[e] + atomicAdd(&curl[e], 1);
    stok[p] = f >> 3;
    se[p] = e;
    sw[p] = wsm[f];
    ipos[f] = p;
  }
}

// ---------------------------------------------------------------- L4: fold pre + gate/up core (fp32) -> bf16
__global__ __launch_bounds__(256) void k_core_gu(const float* __restrict__ Pgp,
                                                 const float* __restrict__ Pup,
                                                 const float* __restrict__ core_g,
                                                 const float* __restrict__ core_u,
                                                 const int* __restrict__ stok,
                                                 const int* __restrict__ se,
                                                 unsigned short* __restrict__ xgb,
                                                 unsigned short* __restrict__ xub) {
  int pl = threadIdx.x >> 6;
  int o = threadIdx.x & 63;
  int p = blockIdx.x * 4 + pl;
  int e = se[p];
  int t = stok[p];
  int g = e >> 5;
  __shared__ float rg[4][64], ru[4][64];
  float sg = 0.f, su = 0.f;
#pragma unroll
  for (int kz = 0; kz < PKZ_; ++kz) {
    sg += Pgp[((size_t)(kz * G_ + g) * T_ + t) * R_ + o];
    su += Pup[((size_t)(kz * G_ + g) * T_ + t) * R_ + o];
  }
  rg[pl][o] = sg;
  ru[pl][o] = su;
  __syncthreads();
  const float* cg = core_g + (size_t)e * R_ * R_;
  const float* cu = core_u + (size_t)e * R_ * R_;
  float ag = 0.f, au = 0.f;
#pragma unroll 8
  for (int r = 0; r < R_; ++r) {
    ag = fmaf(rg[pl][r], cg[r * R_ + o], ag);
    au = fmaf(ru[pl][r], cu[r * R_ + o], au);
  }
  xgb[(size_t)p * R_ + o] = f2bf(ag);
  xub[(size_t)p * R_ + o] = f2bf(au);
}

// ---------------------------------------------------------------- L5: fused act+down (MFMA)
__global__ __launch_bounds__(256) void k_fused_ad(const unsigned short* __restrict__ xgb,
                                                  const unsigned short* __restrict__ xub,
                                                  const unsigned short* __restrict__ uoutT_g,
                                                  const unsigned short* __restrict__ uoutT_u,
                                                  const unsigned short* __restrict__ uinT_d,
                                                  const int* __restrict__ off,
                                                  float* __restrict__ xdp) {
  int g = blockIdx.y;
  int kz = blockIdx.z;
  int p0 = off[g * E_];
  int pend = off[g * E_ + E_];
  int ntiles = (pend - p0 + 63) >> 6;
  __shared__ short Ag[64 * LP_], Au[64 * LP_];
  __shared__ short Bg[64 * LP_], Bu[64 * LP_], Bd[64 * LP_];
  __shared__ short Pt[64 * LP_];
  int tid = threadIdx.x, lane = tid & 63, ms = (tid >> 6) * 16;
  int lm = lane & 15, lq = (lane >> 4) * 4;
  for (int tile = blockIdx.x; tile < ntiles; tile += gridDim.x) {
    int pbase = p0 + tile * 64;
    int rv = pend - pbase; if (rv > 64) rv = 64;
    stage_tile_guard(Ag, xgb + (size_t)pbase * R_, R_, rv, tid);
    stage_tile_guard(Au, xub + (size_t)pbase * R_, R_, rv, tid);
    f32x4 accd[4] = {};
#pragma unroll
    for (int c4 = 0; c4 < 4; ++c4) {
      int cc = kz * (DFF_ / DKZ_) + c4 * 64;
      stage_tile(Bg, uoutT_g + ((size_t)g * DFF_ + cc) * R_, R_, tid);
      stage_tile(Bu, uoutT_u + ((size_t)g * DFF_ + cc) * R_, R_, tid);
      stage_tile(Bd, uinT_d + (size_t)g * 64 * 1024 + cc, 1024, tid);
      __syncthreads();
      f32x4 accg[4] = {}, accu[4] = {};
      mma_strip(Ag, Bg, ms, lane, accg);
      mma_strip(Au, Bu, ms, lane, accu);
#pragma unroll
      for (int nt = 0; nt < 4; ++nt)
#pragma unroll
        for (int r = 0; r < 4; ++r) {
          float gv = accg[nt][r];
          float av = gv / (1.f + expf(-gv)) * accu[nt][r];
          Pt[(ms + lq + r) * LP_ + nt * 16 + lm] = (short)f2bf(av);
        }
      mma_strip(Pt, Bd, ms, lane, accd);  // reads only own-wave rows of Pt
      __syncthreads();
    }
#pragma unroll
    for (int nt = 0; nt < 4; ++nt)
#pragma unroll
      for (int r = 0; r < 4; ++r) {
        int p = pbase + ms + lq + r;
        if (p < pend) xdp[((size_t)kz * F_ + p) * R_ + nt * 16 + lm] = accd[nt][r];
      }
    __syncthreads();
  }
}

// ---------------------------------------------------------------- L6: fold + down core (fp32) -> bf16
__global__ __launch_bounds__(256) void k_core_down(const float* __restrict__ xdp,
                                                   const float* __restrict__ core_d,
                                                   const int* __restrict__ se,
                                                   unsigned short* __restrict__ xd2b) {
  int pl = threadIdx.x >> 6;
  int o = threadIdx.x & 63;
  int p = blockIdx.x * 4 + pl;
  int e = se[p];
  __shared__ float rg[4][64];
  float s = 0.f;
#pragma unroll
  for (int kz = 0; kz < DKZ_; ++kz) s += xdp[((size_t)kz * F_ + p) * R_ + o];
  rg[pl][o] = s;
  __syncthreads();
  const float* cd = core_d + (size_t)e * R_ * R_;
  float a = 0.f;
#pragma unroll 8
  for (int r = 0; r < R_; ++r) a = fmaf(rg[pl][r], cd[r * R_ + o], a);
  xd2b[(size_t)p * R_ + o] = f2bf(a);
}

// ---------------------------------------------------------------- L7: Y[t][g][r] = sum_{k in t, g_k=g} w_k*xd2[p_k][r]
// 256 blocks x 256 thr = 4 tokens/block, thread o = r index.
__global__ __launch_bounds__(256) void k_accY(const unsigned short* __restrict__ xd2b,
                                              const int* __restrict__ ipos,
                                              const int* __restrict__ se,
                                              const float* __restrict__ sw,
                                              unsigned short* __restrict__ Ybf) {
  int t = blockIdx.x * 4 + (threadIdx.x >> 6);
  int o = threadIdx.x & 63;
  float y[G_] = {};
#pragma unroll
  for (int k = 0; k < K_; ++k) {
    int p = ipos[t * K_ + k];
    int g = se[p] >> 5;
    y[g] += sw[p] * bf2f(xd2b[(size_t)p * R_ + o]);
  }
#pragma unroll
  for (int g = 0; g < G_; ++g)
    Ybf[(size_t)t * 512 + g * 64 + o] = f2bf(y[g]);
}

// ---------------------------------------------------------------- L8: out = Y[1024,512] @ Uod2[512,1024], dense MFMA
// grid (16 t-tiles, 16 d-tiles). Uod2T[d][g*64+r] (k-contig rows).
__global__ __launch_bounds__(256) void k_fin(const unsigned short* __restrict__ Ybf,
                                             const unsigned short* __restrict__ Uod2T,
                                             float* __restrict__ out) {
  int t0 = blockIdx.x * 64;
  int d0 = blockIdx.y * 64;
  __shared__ short As[64 * LP_], Bs[64 * LP_];
  __shared__ float Os[64 * 68];
  int tid = threadIdx.x, lane = tid & 63, ms = (tid >> 6) * 16;
  int lm = lane & 15, lq = (lane >> 4) * 4;
  f32x4 acc[4] = {};
  for (int kc = 0; kc < 512; kc += 64) {
    stage_tile(As, Ybf + (size_t)t0 * 512 + kc, 512, tid);
    stage_tile(Bs, Uod2T + (size_t)d0 * 512 + kc, 512, tid);
    __syncthreads();
    mma_strip(As, Bs, ms, lane, acc);
    __syncthreads();
  }
#pragma unroll
  for (int nt = 0; nt < 4; ++nt)
#pragma unroll
    for (int r = 0; r < 4; ++r)
      Os[(ms + lq + r) * 68 + nt * 16 + lm] = acc[nt][r];
  __syncthreads();
  for (int idx = tid; idx < 1024; idx += 256) {
    int r = idx >> 4, c4 = (idx & 15) << 2;
    *(float4*)&out[(size_t)(t0 + r) * D_ + d0 + c4] = *(const float4*)&Os[r * 68 + c4];
  }
}

// ================================================================ launch
extern "C" void kernel_launch(void* const* d_in, const int* in_sizes, int n_in,
                              void* d_out, int out_size, void* d_ws, size_t ws_size,
                              hipStream_t stream) {
  const float* x = (const float*)d_in[0];
  const float* Wg = (const float*)d_in[1];
  const float* uin_gate = (const float*)d_in[2];
  const float* core_gate = (const float*)d_in[3];
  const float* uout_gate = (const float*)d_in[4];
  const float* uin_up = (const float*)d_in[5];
  const float* core_up = (const float*)d_in[6];
  const float* uout_up = (const float*)d_in[7];
  const float* uin_down = (const float*)d_in[8];
  const float* core_down = (const float*)d_in[9];
  const float* uout_down = (const float*)d_in[10];
  float* out = (float*)d_out;

  char* ws = (char*)d_ws;
  size_t o = 0;
  auto alloc = [&](size_t bytes) { size_t r = o; o = (o + bytes + 255) & ~(size_t)255; return r; };
  size_t o_lp = alloc((size_t)LKZ_ * T_ * NEXP_ * 4);           // 8 MB
  size_t o_sel = alloc(F_ * 4);
  size_t o_wsm = alloc(F_ * 4);
  size_t o_cnt = alloc(NEXP_ * 4);
  size_t o_off = alloc((NEXP_ + 1) * 4);
  size_t o_stok = alloc(F_ * 4);
  size_t o_se = alloc(F_ * 4);
  size_t o_sw = alloc(F_ * 4);
  size_t o_ipos = alloc(F_ * 4);
  size_t o_xb = alloc((size_t)T_ * D_ * 2);                     // 2 MB
  size_t o_uinT_g = alloc((size_t)G_ * 64 * 1024 * 2);          // 1 MB each
  size_t o_uinT_u = alloc((size_t)G_ * 64 * 1024 * 2);
  size_t o_uinT_d = alloc((size_t)G_ * 64 * 1024 * 2);
  size_t o_uoutT_g = alloc((size_t)G_ * 1024 * 64 * 2);
  size_t o_uoutT_u = alloc((size_t)G_ * 1024 * 64 * 2);
  size_t o_Uod2T = alloc((size_t)D_ * 512 * 2);                 // 1 MB
  size_t o_xgb = alloc((size_t)F_ * R_ * 2);                    // 1 MB
  size_t o_xub = alloc((size_t)F_ * R_ * 2);
  size_t o_xd2b = alloc((size_t)F_ * R_ * 2);
  size_t o_Y = alloc((size_t)T_ * 512 * 2);                     // 1 MB
  size_t o_pgp = alloc((size_t)PKZ_ * G_ * T_ * R_ * 4);        // 4 MB
  size_t o_pup = alloc((size_t)PKZ_ * G_ * T_ * R_ * 4);        // 4 MB
  size_t o_xdp = alloc((size_t)DKZ_ * F_ * R_ * 4);             // 8 MB
  (void)ws_size;

  float* lp = (float*)(ws + o_lp);
  int* sel = (int*)(ws + o_sel);
  float* wsm = (float*)(ws + o_wsm);
  int* cnt = (int*)(ws + o_cnt);
  int* off = (int*)(ws + o_off);
  int* stok = (int*)(ws + o_stok);
  int* se = (int*)(ws + o_se);
  float* sw = (float*)(ws + o_sw);
  int* ipos = (int*)(ws + o_ipos);
  unsigned short* xb = (unsigned short*)(ws + o_xb);
  unsigned short* uinT_g = (unsigned short*)(ws + o_uinT_g);
  unsigned short* uinT_u = (unsigned short*)(ws + o_uinT_u);
  unsigned short* uinT_d = (unsigned short*)(ws + o_uinT_d);
  unsigned short* uoutT_g = (unsigned short*)(ws + o_uoutT_g);
  unsigned short* uoutT_u = (unsigned short*)(ws + o_uoutT_u);
  unsigned short* Uod2T = (unsigned short*)(ws + o_Uod2T);
  unsigned short* xgb = (unsigned short*)(ws + o_xgb);
  unsigned short* xub = (unsigned short*)(ws + o_xub);
  unsigned short* xd2b = (unsigned short*)(ws + o_xd2b);
  unsigned short* Ybf = (unsigned short*)(ws + o_Y);
  float* pgp = (float*)(ws + o_pgp);
  float* pup = (float*)(ws + o_pup);
  float* xdp = (float*)(ws + o_xdp);

  k_prep_logits<<<1920, 256, 0, stream>>>(x, Wg, uin_gate, uin_up, uin_down,
                                          uout_gate, uout_up, uout_down, xb,
                                          uinT_g, uinT_u, uinT_d,
                                          uoutT_g, uoutT_u, Uod2T, cnt, lp);
  k_pre_topk<<<768, 256, 0, stream>>>(xb, uinT_g, uinT_u, lp, pgp, pup, sel, wsm, cnt);
  k_sortscan<<<1, 1024, 0, stream>>>(cnt, sel, wsm, off, stok, se, sw, ipos);
  k_core_gu<<<F_ / 4, 256, 0, stream>>>(pgp, pup, core_gate, core_up, stok, se, xgb, xub);
  k_fused_ad<<<dim3(16, G_, DKZ_), 256, 0, stream>>>(xgb, xub, uoutT_g, uoutT_u, uinT_d, off, xdp);
  k_core_down<<<F_ / 4, 256, 0, stream>>>(xdp, core_down, se, xd2b);
  k_accY<<<T_ / 4, 256, 0, stream>>>(xd2b, ipos, se, sw, Ybf);
  k_fin<<<dim3(16, 16), 256, 0, stream>>>(Ybf, Uod2T, out);
}

// Round 9
// 201.943 us; speedup vs baseline: 1.3820x; 1.0953x over previous
//
#include <hip/hip_runtime.h>
#include <hip/hip_bf16.h>
#include <math.h>

// Tucker MoE: T=1024, D=1024, DFF=1024, R=64, G=8, E=32, NEXP=256, K=8, F=8192
// Round 9: delete the scatter. k_topk keeps the atomicAdd return as rank[f];
// any consumer computes p = off[e] + rank[f] on the fly, so:
//  - k_scan is a bare 256-entry scan (1 block, ~2us; 8192-item scatter gone)
//  - stok/se/sw-by-p/ipos arrays deleted
//  - k_core_down + k_accY merged into token-centric k_down_accY
// 7 dispatches:
//  L1 k_prep_logits : casts/transposes + cnt zero || router logits (fp32)
//  L2 k_pre_topk    : pre MFMA (split-K 2) || top-k + softmax + rank
//  L3 k_scan        : 256-entry scan -> off
//  L4 k_core_gu     : f-indexed fold pre + gate/up core (fp32) -> xgb/xub[p]
//  L5 k_fused_ad    : act(gate/up MFMA + silu*mul in LDS) fused w/ down MFMA
//  L6 k_down_accY   : fold xdp + down core + weighted token fold -> Y bf16
//  L7 k_fin         : dense out = Y[1024,512] @ Uod2[512,1024] (bf16 MFMA)

#define T_ 1024
#define D_ 1024
#define DFF_ 1024
#define R_ 64
#define G_ 8
#define E_ 32
#define NEXP_ 256
#define K_ 8
#define F_ 8192
#define LKZ_ 8   // router split-K (chunks of 128)
#define LTB_ 8   // router tokens per block
#define PKZ_ 2   // k_pre split-K
#define DKZ_ 4   // down split-K (chunks of 256 over DFF)
#define LP_ 72   // LDS tile pitch in bf16 elems (16B rows, 2-way bank alias = free)

typedef short bf16x8 __attribute__((ext_vector_type(8)));
typedef float f32x4 __attribute__((ext_vector_type(4)));

__device__ __forceinline__ unsigned short f2bf(float f) {
  unsigned int u = __float_as_uint(f);
  u += 0x7fffu + ((u >> 16) & 1u);  // RNE (finite inputs)
  return (unsigned short)(u >> 16);
}

__device__ __forceinline__ void stage_tile(short* dst, const unsigned short* src,
                                           int gp, int tid) {
  for (int idx = tid; idx < 512; idx += 256) {
    int r = idx >> 3, c8 = (idx & 7) << 3;
    *(uint4*)&dst[r * LP_ + c8] = *(const uint4*)&src[(size_t)r * gp + c8];
  }
}

__device__ __forceinline__ void stage_tile_guard(short* dst, const unsigned short* src,
                                                 int gp, int rows_valid, int tid) {
  for (int idx = tid; idx < 512; idx += 256) {
    int r = idx >> 3, c8 = (idx & 7) << 3;
    uint4 v = make_uint4(0u, 0u, 0u, 0u);
    if (r < rows_valid) v = *(const uint4*)&src[(size_t)r * gp + c8];
    *(uint4*)&dst[r * LP_ + c8] = v;
  }
}

// Wave computes a 16x64 strip (rows [ms,ms+16)) over K=64 from LDS tiles
// As (rows=m, k-contig) and Bs (rows=n, k-contig; i.e. B^T).
__device__ __forceinline__ void mma_strip(const short* As, const short* Bs,
                                          int ms, int lane, f32x4* acc) {
  int lm = lane & 15;
  int lk = (lane >> 4) << 3;
#pragma unroll
  for (int kc = 0; kc < 64; kc += 32) {
    bf16x8 a = *(const bf16x8*)&As[(ms + lm) * LP_ + kc + lk];
#pragma unroll
    for (int nt = 0; nt < 4; ++nt) {
      bf16x8 b = *(const bf16x8*)&Bs[(nt * 16 + lm) * LP_ + kc + lk];
      acc[nt] = __builtin_amdgcn_mfma_f32_16x16x32_bf16(a, b, acc[nt], 0, 0, 0);
    }
  }
}

// ---------------------------------------------------------------- L1: prep || logits
// 1D grid of 1920 blocks: b<896 = prep roles (id=b>>7: 0..4 cast+T,
// id 5 = uout_down -> Uod2T[d][g*64+r]; 6 = x cast + cnt zero);
// b>=896 = router logits split-K (1024 blocks).
__global__ __launch_bounds__(256) void k_prep_logits(
    const float* __restrict__ x, const float* __restrict__ Wg,
    const float* __restrict__ s0, const float* __restrict__ s1,
    const float* __restrict__ s2, const float* __restrict__ s3,
    const float* __restrict__ s4, const float* __restrict__ s5,
    unsigned short* __restrict__ xb,
    unsigned short* __restrict__ d0, unsigned short* __restrict__ d1,
    unsigned short* __restrict__ d2, unsigned short* __restrict__ d3,
    unsigned short* __restrict__ d4, unsigned short* __restrict__ d5,
    int* __restrict__ cnt, float* __restrict__ lp) {
  __shared__ float shbuf[64 * 65];  // prep: ts[64][65]; logits: xs[8][128]
  int b = blockIdx.x;
  if (b < 896) {
    int id = b >> 7, rem = b & 127, g = rem >> 4, tile = rem & 15;
    if (id == 6) {
      size_t base = ((size_t)g * 16 + tile) * 8192;
      for (int i = threadIdx.x; i < 2048; i += 256) {
        size_t idx = base + (size_t)i * 4;
        float4 v = *(const float4*)&x[idx];
        xb[idx + 0] = f2bf(v.x);
        xb[idx + 1] = f2bf(v.y);
        xb[idx + 2] = f2bf(v.z);
        xb[idx + 3] = f2bf(v.w);
      }
      if (g == 0 && tile == 0) cnt[threadIdx.x] = 0;
      return;
    }
    const float* src = id == 0 ? s0 : id == 1 ? s1 : id == 2 ? s2 : id == 3 ? s3 : id == 4 ? s4 : s5;
    unsigned short* dst = id == 0 ? d0 : id == 1 ? d1 : id == 2 ? d2 : id == 3 ? d3 : id == 4 ? d4 : d5;
    if (id < 3) {
      // uin*: src [g][1024][64] -> dst [g][64][1024]
      int r0 = tile * 64;
      for (int idx = threadIdx.x; idx < 4096; idx += 256) {
        int r = idx >> 6, c = idx & 63;
        shbuf[r * 65 + c] = src[((size_t)g * 1024 + r0 + r) * 64 + c];
      }
      __syncthreads();
      for (int idx = threadIdx.x; idx < 4096; idx += 256) {
        int c = idx >> 6, r = idx & 63;
        dst[((size_t)g * 64 + c) * 1024 + r0 + r] = f2bf(shbuf[r * 65 + c]);
      }
    } else {
      // uout*: src [g][64][1024]; id 3/4 -> [g][1024][64]; id 5 -> [d][g*64+r]
      int c0 = tile * 64;
      for (int idx = threadIdx.x; idx < 4096; idx += 256) {
        int r = idx >> 6, c = idx & 63;
        shbuf[r * 65 + c] = src[((size_t)g * 64 + r) * 1024 + c0 + c];
      }
      __syncthreads();
      if (id == 5) {
        for (int idx = threadIdx.x; idx < 4096; idx += 256) {
          int c = idx >> 6, r = idx & 63;
          dst[(size_t)(c0 + c) * 512 + g * 64 + r] = f2bf(shbuf[r * 65 + c]);
        }
      } else {
        for (int idx = threadIdx.x; idx < 4096; idx += 256) {
          int c = idx >> 6, r = idx & 63;
          dst[((size_t)g * 1024 + c0 + c) * 64 + r] = f2bf(shbuf[r * 65 + c]);
        }
      }
    }
    return;
  }
  // ---- router logits: lp[z][t][e], 8 tokens/block, K-chunk of 128
  int lb = b - 896;
  int t0 = (lb & 127) * LTB_;
  int z = lb >> 7;
  int e = threadIdx.x;
  float* xs = shbuf;  // [8][128]
  float a[LTB_] = {};
  int dc = z * 128;
  {
    int idx = threadIdx.x * 4;  // 256 thr x float4 = the whole 8x128 tile
    int tl = idx >> 7, d = idx & 127;
    *(float4*)&xs[tl * 128 + d] = *(const float4*)&x[(size_t)(t0 + tl) * D_ + dc + d];
  }
  __syncthreads();
#pragma unroll 8
  for (int d2 = 0; d2 < 128; ++d2) {
    float wv = Wg[(size_t)(dc + d2) * NEXP_ + e];
#pragma unroll
    for (int j = 0; j < LTB_; ++j) a[j] = fmaf(xs[j * 128 + d2], wv, a[j]);
  }
  size_t base = (size_t)z * T_ * NEXP_;
#pragma unroll
  for (int j = 0; j < LTB_; ++j)
    lp[base + (size_t)(t0 + j) * NEXP_ + e] = a[j];
}

// ---------------------------------------------------------------- L2: pre MFMA || topk (+rank)
__global__ __launch_bounds__(256) void k_pre_topk(
    const unsigned short* __restrict__ xb,
    const unsigned short* __restrict__ uinT_g, const unsigned short* __restrict__ uinT_u,
    const float* __restrict__ lp,
    float* __restrict__ Pgp, float* __restrict__ Pup,
    int* __restrict__ sel, float* __restrict__ wsm,
    int* __restrict__ rank, int* __restrict__ cnt) {
  __shared__ short sh2[2 * 64 * LP_];
  int b = blockIdx.x;
  if (b < 512) {
    int tile = b & 15, g = (b >> 4) & 7, zz = b >> 7;
    int gu = zz >> 1, kz = zz & 1;
    const unsigned short* U = gu ? uinT_u : uinT_g;  // [G][64(r)][1024(d)]
    float* P = gu ? Pup : Pgp;
    int t0 = tile * 64;
    short* As = sh2;
    short* Bs = sh2 + 64 * LP_;
    int tid = threadIdx.x, lane = tid & 63, ms = (tid >> 6) * 16;
    f32x4 acc[4] = {};
    int dlo = kz * (D_ / PKZ_);
    for (int dc = dlo; dc < dlo + D_ / PKZ_; dc += 64) {
      stage_tile(As, xb + (size_t)t0 * D_ + dc, D_, tid);
      stage_tile(Bs, U + (size_t)g * 64 * 1024 + dc, 1024, tid);
      __syncthreads();
      mma_strip(As, Bs, ms, lane, acc);
      __syncthreads();
    }
    int lm = lane & 15, lq = (lane >> 4) * 4;
#pragma unroll
    for (int nt = 0; nt < 4; ++nt)
#pragma unroll
      for (int r = 0; r < 4; ++r)
        P[((size_t)(kz * G_ + g) * T_ + t0 + ms + lq + r) * R_ + nt * 16 + lm] = acc[nt][r];
    return;
  }
  // ---- topk: one wave per token, folds the LKZ_ logits partials on load
  int tb = b - 512;
  int wave = threadIdx.x >> 6;
  int lane = threadIdx.x & 63;
  int t = tb * 4 + wave;
  float v[4];
  int idx[4];
#pragma unroll
  for (int j = 0; j < 4; ++j) {
    idx[j] = lane + 64 * j;
    float s = 0.f;
#pragma unroll
    for (int z = 0; z < LKZ_; ++z)
      s += lp[(size_t)z * T_ * NEXP_ + (size_t)t * NEXP_ + idx[j]];
    v[j] = s;
  }
  float topv[K_];
  int topi[K_];
#pragma unroll
  for (int k = 0; k < K_; ++k) {
    float bv = v[0];
    int bi = idx[0];
#pragma unroll
    for (int j = 1; j < 4; ++j)
      if (v[j] > bv || (v[j] == bv && idx[j] < bi)) { bv = v[j]; bi = idx[j]; }
#pragma unroll
    for (int off = 32; off > 0; off >>= 1) {
      float ov = __shfl_xor(bv, off);
      int oi = __shfl_xor(bi, off);
      if (ov > bv || (ov == bv && oi < bi)) { bv = ov; bi = oi; }
    }
    topv[k] = bv;
    topi[k] = bi;
#pragma unroll
    for (int j = 0; j < 4; ++j)
      if (idx[j] == bi) v[j] = -INFINITY;
  }
  float m = topv[0];
  float ev[K_];
  float s = 0.f;
#pragma unroll
  for (int k = 0; k < K_; ++k) { ev[k] = expf(topv[k] - m); s += ev[k]; }
  float inv = 1.f / s;
  if (lane < K_) {
    sel[t * K_ + lane] = topi[lane];
    wsm[t * K_ + lane] = ev[lane] * inv;
    rank[t * K_ + lane] = atomicAdd(&cnt[topi[lane]], 1);  // keep the rank!
  }
}

// ---------------------------------------------------------------- L3: bare 256-entry scan -> off
__global__ __launch_bounds__(256) void k_scan(const int* __restrict__ cnt,
                                              int* __restrict__ off) {
  __shared__ int s[NEXP_];
  int i = threadIdx.x;
  s[i] = cnt[i];
  __syncthreads();
  for (int d = 1; d < NEXP_; d <<= 1) {
    int v = (i >= d) ? s[i - d] : 0;
    __syncthreads();
    s[i] += v;
    __syncthreads();
  }
  off[i + 1] = s[i];
  if (i == 0) off[0] = 0;
}

// ---------------------------------------------------------------- L4: f-indexed fold pre + gate/up core -> xgb/xub[p]
__global__ __launch_bounds__(256) void k_core_gu(const float* __restrict__ Pgp,
                                                 const float* __restrict__ Pup,
                                                 const float* __restrict__ core_g,
                                                 const float* __restrict__ core_u,
                                                 const int* __restrict__ sel,
                                                 const int* __restrict__ rank,
                                                 const int* __restrict__ off,
                                                 unsigned short* __restrict__ xgb,
                                                 unsigned short* __restrict__ xub) {
  int pl = threadIdx.x >> 6;
  int o = threadIdx.x & 63;
  int f = blockIdx.x * 4 + pl;
  int t = f >> 3;
  int e = sel[f];
  int g = e >> 5;
  int p = off[e] + rank[f];
  __shared__ float rg[4][64], ru[4][64];
  float sg = 0.f, su = 0.f;
#pragma unroll
  for (int kz = 0; kz < PKZ_; ++kz) {
    sg += Pgp[((size_t)(kz * G_ + g) * T_ + t) * R_ + o];
    su += Pup[((size_t)(kz * G_ + g) * T_ + t) * R_ + o];
  }
  rg[pl][o] = sg;
  ru[pl][o] = su;
  __syncthreads();
  const float* cg = core_g + (size_t)e * R_ * R_;
  const float* cu = core_u + (size_t)e * R_ * R_;
  float ag = 0.f, au = 0.f;
#pragma unroll 8
  for (int r = 0; r < R_; ++r) {
    ag = fmaf(rg[pl][r], cg[r * R_ + o], ag);
    au = fmaf(ru[pl][r], cu[r * R_ + o], au);
  }
  xgb[(size_t)p * R_ + o] = f2bf(ag);
  xub[(size_t)p * R_ + o] = f2bf(au);
}

// ---------------------------------------------------------------- L5: fused act+down (MFMA)
__global__ __launch_bounds__(256) void k_fused_ad(const unsigned short* __restrict__ xgb,
                                                  const unsigned short* __restrict__ xub,
                                                  const unsigned short* __restrict__ uoutT_g,
                                                  const unsigned short* __restrict__ uoutT_u,
                                                  const unsigned short* __restrict__ uinT_d,
                                                  const int* __restrict__ off,
                                                  float* __restrict__ xdp) {
  int g = blockIdx.y;
  int kz = blockIdx.z;
  int p0 = off[g * E_];
  int pend = off[g * E_ + E_];
  int ntiles = (pend - p0 + 63) >> 6;
  __shared__ short Ag[64 * LP_], Au[64 * LP_];
  __shared__ short Bg[64 * LP_], Bu[64 * LP_], Bd[64 * LP_];
  __shared__ short Pt[64 * LP_];
  int tid = threadIdx.x, lane = tid & 63, ms = (tid >> 6) * 16;
  int lm = lane & 15, lq = (lane >> 4) * 4;
  for (int tile = blockIdx.x; tile < ntiles; tile += gridDim.x) {
    int pbase = p0 + tile * 64;
    int rv = pend - pbase; if (rv > 64) rv = 64;
    stage_tile_guard(Ag, xgb + (size_t)pbase * R_, R_, rv, tid);
    stage_tile_guard(Au, xub + (size_t)pbase * R_, R_, rv, tid);
    f32x4 accd[4] = {};
#pragma unroll
    for (int c4 = 0; c4 < 4; ++c4) {
      int cc = kz * (DFF_ / DKZ_) + c4 * 64;
      stage_tile(Bg, uoutT_g + ((size_t)g * DFF_ + cc) * R_, R_, tid);
      stage_tile(Bu, uoutT_u + ((size_t)g * DFF_ + cc) * R_, R_, tid);
      stage_tile(Bd, uinT_d + (size_t)g * 64 * 1024 + cc, 1024, tid);
      __syncthreads();
      f32x4 accg[4] = {}, accu[4] = {};
      mma_strip(Ag, Bg, ms, lane, accg);
      mma_strip(Au, Bu, ms, lane, accu);
#pragma unroll
      for (int nt = 0; nt < 4; ++nt)
#pragma unroll
        for (int r = 0; r < 4; ++r) {
          float gv = accg[nt][r];
          float av = gv / (1.f + expf(-gv)) * accu[nt][r];
          Pt[(ms + lq + r) * LP_ + nt * 16 + lm] = (short)f2bf(av);
        }
      mma_strip(Pt, Bd, ms, lane, accd);  // reads only own-wave rows of Pt
      __syncthreads();
    }
#pragma unroll
    for (int nt = 0; nt < 4; ++nt)
#pragma unroll
      for (int r = 0; r < 4; ++r) {
        int p = pbase + ms + lq + r;
        if (p < pend) xdp[((size_t)kz * F_ + p) * R_ + nt * 16 + lm] = accd[nt][r];
      }
    __syncthreads();
  }
}

// ---------------------------------------------------------------- L6: fold xdp + down core + token fold -> Y bf16
// 1024 blocks = 1 token each. Wave w handles k = 2w, 2w+1 (lane = r/output o).
__global__ __launch_bounds__(256) void k_down_accY(const float* __restrict__ xdp,
                                                   const float* __restrict__ core_d,
                                                   const int* __restrict__ sel,
                                                   const int* __restrict__ rank,
                                                   const float* __restrict__ wsm,
                                                   const int* __restrict__ off,
                                                   unsigned short* __restrict__ Ybf) {
  int t = blockIdx.x;
  int w = threadIdx.x >> 6, o = threadIdx.x & 63;
  __shared__ float xs[4][64];
  __shared__ float yl[4][G_][64];
  float y[G_] = {};
#pragma unroll
  for (int kk = 0; kk < 2; ++kk) {
    int f = t * K_ + w * 2 + kk;
    int e = sel[f];
    int g = e >> 5;
    int p = off[e] + rank[f];
    float s = 0.f;
#pragma unroll
    for (int kz = 0; kz < DKZ_; ++kz) s += xdp[((size_t)kz * F_ + p) * R_ + o];
    __syncthreads();
    xs[w][o] = s;
    __syncthreads();
    const float* cd = core_d + (size_t)e * R_ * R_;
    float a = 0.f;
#pragma unroll 8
    for (int r = 0; r < R_; ++r) a = fmaf(xs[w][r], cd[r * R_ + o], a);
    y[g] += wsm[f] * a;
  }
#pragma unroll
  for (int g = 0; g < G_; ++g) yl[w][g][o] = y[g];
  __syncthreads();
  for (int idx = threadIdx.x; idx < 512; idx += 256) {
    int g = idx >> 6, oo = idx & 63;
    float v = yl[0][g][oo] + yl[1][g][oo] + yl[2][g][oo] + yl[3][g][oo];
    Ybf[(size_t)t * 512 + g * 64 + oo] = f2bf(v);
  }
}

// ---------------------------------------------------------------- L7: out = Y[1024,512] @ Uod2[512,1024], dense MFMA
__global__ __launch_bounds__(256) void k_fin(const unsigned short* __restrict__ Ybf,
                                             const unsigned short* __restrict__ Uod2T,
                                             float* __restrict__ out) {
  int t0 = blockIdx.x * 64;
  int d0 = blockIdx.y * 64;
  __shared__ short As[64 * LP_], Bs[64 * LP_];
  __shared__ float Os[64 * 68];
  int tid = threadIdx.x, lane = tid & 63, ms = (tid >> 6) * 16;
  int lm = lane & 15, lq = (lane >> 4) * 4;
  f32x4 acc[4] = {};
  for (int kc = 0; kc < 512; kc += 64) {
    stage_tile(As, Ybf + (size_t)t0 * 512 + kc, 512, tid);
    stage_tile(Bs, Uod2T + (size_t)d0 * 512 + kc, 512, tid);
    __syncthreads();
    mma_strip(As, Bs, ms, lane, acc);
    __syncthreads();
  }
#pragma unroll
  for (int nt = 0; nt < 4; ++nt)
#pragma unroll
    for (int r = 0; r < 4; ++r)
      Os[(ms + lq + r) * 68 + nt * 16 + lm] = acc[nt][r];
  __syncthreads();
  for (int idx = tid; idx < 1024; idx += 256) {
    int r = idx >> 4, c4 = (idx & 15) << 2;
    *(float4*)&out[(size_t)(t0 + r) * D_ + d0 + c4] = *(const float4*)&Os[r * 68 + c4];
  }
}

// ================================================================ launch
extern "C" void kernel_launch(void* const* d_in, const int* in_sizes, int n_in,
                              void* d_out, int out_size, void* d_ws, size_t ws_size,
                              hipStream_t stream) {
  const float* x = (const float*)d_in[0];
  const float* Wg = (const float*)d_in[1];
  const float* uin_gate = (const float*)d_in[2];
  const float* core_gate = (const float*)d_in[3];
  const float* uout_gate = (const float*)d_in[4];
  const float* uin_up = (const float*)d_in[5];
  const float* core_up = (const float*)d_in[6];
  const float* uout_up = (const float*)d_in[7];
  const float* uin_down = (const float*)d_in[8];
  const float* core_down = (const float*)d_in[9];
  const float* uout_down = (const float*)d_in[10];
  float* out = (float*)d_out;

  char* ws = (char*)d_ws;
  size_t o = 0;
  auto alloc = [&](size_t bytes) { size_t r = o; o = (o + bytes + 255) & ~(size_t)255; return r; };
  size_t o_lp = alloc((size_t)LKZ_ * T_ * NEXP_ * 4);           // 8 MB
  size_t o_sel = alloc(F_ * 4);
  size_t o_wsm = alloc(F_ * 4);
  size_t o_rank = alloc(F_ * 4);
  size_t o_cnt = alloc(NEXP_ * 4);
  size_t o_off = alloc((NEXP_ + 1) * 4);
  size_t o_xb = alloc((size_t)T_ * D_ * 2);                     // 2 MB
  size_t o_uinT_g = alloc((size_t)G_ * 64 * 1024 * 2);          // 1 MB each
  size_t o_uinT_u = alloc((size_t)G_ * 64 * 1024 * 2);
  size_t o_uinT_d = alloc((size_t)G_ * 64 * 1024 * 2);
  size_t o_uoutT_g = alloc((size_t)G_ * 1024 * 64 * 2);
  size_t o_uoutT_u = alloc((size_t)G_ * 1024 * 64 * 2);
  size_t o_Uod2T = alloc((size_t)D_ * 512 * 2);                 // 1 MB
  size_t o_xgb = alloc((size_t)F_ * R_ * 2);                    // 1 MB
  size_t o_xub = alloc((size_t)F_ * R_ * 2);
  size_t o_Y = alloc((size_t)T_ * 512 * 2);                     // 1 MB
  size_t o_pgp = alloc((size_t)PKZ_ * G_ * T_ * R_ * 4);        // 4 MB
  size_t o_pup = alloc((size_t)PKZ_ * G_ * T_ * R_ * 4);        // 4 MB
  size_t o_xdp = alloc((size_t)DKZ_ * F_ * R_ * 4);             // 8 MB
  (void)ws_size;

  float* lp = (float*)(ws + o_lp);
  int* sel = (int*)(ws + o_sel);
  float* wsm = (float*)(ws + o_wsm);
  int* rank = (int*)(ws + o_rank);
  int* cnt = (int*)(ws + o_cnt);
  int* off = (int*)(ws + o_off);
  unsigned short* xb = (unsigned short*)(ws + o_xb);
  unsigned short* uinT_g = (unsigned short*)(ws + o_uinT_g);
  unsigned short* uinT_u = (unsigned short*)(ws + o_uinT_u);
  unsigned short* uinT_d = (unsigned short*)(ws + o_uinT_d);
  unsigned short* uoutT_g = (unsigned short*)(ws + o_uoutT_g);
  unsigned short* uoutT_u = (unsigned short*)(ws + o_uoutT_u);
  unsigned short* Uod2T = (unsigned short*)(ws + o_Uod2T);
  unsigned short* xgb = (unsigned short*)(ws + o_xgb);
  unsigned short* xub = (unsigned short*)(ws + o_xub);
  unsigned short* Ybf = (unsigned short*)(ws + o_Y);
  float* pgp = (float*)(ws + o_pgp);
  float* pup = (float*)(ws + o_pup);
  float* xdp = (float*)(ws + o_xdp);

  k_prep_logits<<<1920, 256, 0, stream>>>(x, Wg, uin_gate, uin_up, uin_down,
                                          uout_gate, uout_up, uout_down, xb,
                                          uinT_g, uinT_u, uinT_d,
                                          uoutT_g, uoutT_u, Uod2T, cnt, lp);
  k_pre_topk<<<768, 256, 0, stream>>>(xb, uinT_g, uinT_u, lp, pgp, pup, sel, wsm, rank, cnt);
  k_scan<<<1, 256, 0, stream>>>(cnt, off);
  k_core_gu<<<F_ / 4, 256, 0, stream>>>(pgp, pup, core_gate, core_up, sel, rank, off, xgb, xub);
  k_fused_ad<<<dim3(16, G_, DKZ_), 256, 0, stream>>>(xgb, xub, uoutT_g, uoutT_u, uinT_d, off, xdp);
  k_down_accY<<<T_, 256, 0, stream>>>(xdp, core_down, sel, rank, wsm, off, Ybf);
  k_fin<<<dim3(16, 16), 256, 0, stream>>>(Ybf, Uod2T, out);
}